// Round 1
// baseline (285.429 us; speedup 1.0000x reference)
//
#include <hip/hip_runtime.h>
#include <math.h>

#define NPTS 4096
#define NB   4

// ---- workspace offsets (floats); total 14,155,776 floats = 56.6 MB ----
#define OFF_XP    0          // [B][N][512]  in_proj out; later reused as outpre [B][N][256]
#define OFF_XS    8388608    // [B][N][256]  silu(conv) out; later aliased as y
#define OFF_BM    12582912   // [B][N][16]
#define OFF_CM    12845056   // [B][N][16]
#define OFF_CARRY 13107200   // [B][64][256][16]

__device__ __forceinline__ float sigmoidf_(float v) { return 1.f / (1.f + expf(-v)); }

// ===== K1: in_proj GEMM: xp[b][t][o] = sum_c w_in[o][c]*x[b][c][t] + b_in[o]
// grid (N/64, 512/64, B), 256 thr, 64x64 tile, K-step 16, 4x4 micro-tile
__global__ __launch_bounds__(256) void k_inproj(const float* __restrict__ x,
                                                const float* __restrict__ w,
                                                const float* __restrict__ bias,
                                                float* __restrict__ xp) {
  const int b  = blockIdx.z;
  const int o0 = blockIdx.y << 6;
  const int t0 = blockIdx.x << 6;
  const int tid = threadIdx.x;
  __shared__ __align__(16) float Wl[16][64];
  __shared__ __align__(16) float Xl[16][64];
  const int tx = tid & 15, ty = tid >> 4;
  const int wo = tid >> 2, wk = (tid & 3) << 2;
  const int xc = tid >> 4, xt = (tid & 15) << 2;
  float acc[4][4] = {};
  for (int k0 = 0; k0 < 256; k0 += 16) {
    __syncthreads();
    float4 wv = *(const float4*)&w[(o0 + wo) * 256 + k0 + wk];
    Wl[wk + 0][wo] = wv.x;
    Wl[wk + 1][wo] = wv.y;
    Wl[wk + 2][wo] = wv.z;
    Wl[wk + 3][wo] = wv.w;
    *(float4*)&Xl[xc][xt] = *(const float4*)&x[(b * 256 + k0 + xc) * NPTS + t0 + xt];
    __syncthreads();
    #pragma unroll
    for (int k = 0; k < 16; ++k) {
      float4 av = *(float4*)&Wl[k][ty << 2];
      float4 bv = *(float4*)&Xl[k][tx << 2];
      float aa[4] = {av.x, av.y, av.z, av.w};
      float bb[4] = {bv.x, bv.y, bv.z, bv.w};
      #pragma unroll
      for (int i = 0; i < 4; ++i)
        #pragma unroll
        for (int j = 0; j < 4; ++j)
          acc[i][j] = fmaf(aa[i], bb[j], acc[i][j]);
    }
  }
  float4 bi = *(const float4*)&bias[o0 + (ty << 2)];
  float bia[4] = {bi.x, bi.y, bi.z, bi.w};
  #pragma unroll
  for (int j = 0; j < 4; ++j) {
    int t = t0 + (tx << 2) + j;
    float4 ov = make_float4(acc[0][j] + bia[0], acc[1][j] + bia[1],
                            acc[2][j] + bia[2], acc[3][j] + bia[3]);
    *(float4*)&xp[(b * NPTS + t) * 512 + o0 + (ty << 2)] = ov;
  }
}

// ===== K2: depthwise causal conv (w=4) + bias + silu -> xs[b][t][d]
// grid (N/64, B), 256 thr (lane = d), sliding window in registers
__global__ __launch_bounds__(256) void k_conv(const float* __restrict__ xp,
                                              const float* __restrict__ wconv,
                                              const float* __restrict__ bconv,
                                              float* __restrict__ xs) {
  const int b = blockIdx.y, t0 = blockIdx.x << 6, d = threadIdx.x;
  const float4 wc = *(const float4*)&wconv[d << 2];
  const float bc = bconv[d];
  float xm3 = 0.f, xm2 = 0.f, xm1 = 0.f;
  if (t0 > 0) {
    int bb = (b * NPTS + t0) * 512 + d;
    xm3 = xp[bb - 3 * 512];
    xm2 = xp[bb - 2 * 512];
    xm1 = xp[bb - 1 * 512];
  }
  for (int i = 0; i < 64; ++i) {
    int t = t0 + i;
    float xc = xp[(b * NPTS + t) * 512 + d];
    float cv = fmaf(wc.x, xm3, fmaf(wc.y, xm2, fmaf(wc.z, xm1, fmaf(wc.w, xc, bc))));
    xs[(b * NPTS + t) * 256 + d] = cv * sigmoidf_(cv);
    xm3 = xm2; xm2 = xm1; xm1 = xc;
  }
}

// ===== K3: Bm[b][t][s] = sum_d xs[b][t][d]*Bw[s][d];  Cm likewise
// grid (N/16, B), 256 thr; xs tile + Bw/Cw staged in LDS
__global__ __launch_bounds__(256) void k_bc(const float* __restrict__ xs,
                                            const float* __restrict__ Bw,
                                            const float* __restrict__ Cw,
                                            float* __restrict__ Bm,
                                            float* __restrict__ Cm) {
  const int b = blockIdx.y, t0 = blockIdx.x << 4, tid = threadIdx.x;
  __shared__ __align__(16) float xt[16][256];
  __shared__ __align__(16) float Bl[16][260];  // pad 260: lanes (s) land on distinct bank groups
  __shared__ __align__(16) float Cl[16][260];
  #pragma unroll
  for (int r = 0; r < 4; ++r) {
    int lin = (r * 256 + tid) << 2;            // 0..4092, step 4
    int t = lin >> 8, dd = lin & 255;
    *(float4*)&xt[t][dd] = *(const float4*)&xs[(b * NPTS + t0 + t) * 256 + dd];
    int idx = r * 256 + tid;                   // 0..1023
    int s = idx >> 6, dg = (idx & 63) << 2;
    *(float4*)&Bl[s][dg] = *(const float4*)&Bw[s * 256 + dg];
    *(float4*)&Cl[s][dg] = *(const float4*)&Cw[s * 256 + dg];
  }
  __syncthreads();
  const int s = tid & 15, tl = tid >> 4;
  float accB = 0.f, accC = 0.f;
  #pragma unroll 8
  for (int dd = 0; dd < 256; dd += 4) {
    float4 xv = *(float4*)&xt[tl][dd];
    float4 bv = *(float4*)&Bl[s][dd];
    float4 cv = *(float4*)&Cl[s][dd];
    accB += xv.x * bv.x + xv.y * bv.y + xv.z * bv.z + xv.w * bv.w;
    accC += xv.x * cv.x + xv.y * cv.y + xv.z * cv.z + xv.w * cv.w;
  }
  int row = (b * NPTS + t0 + tl) * 16 + s;
  Bm[row] = accB;
  Cm[row] = accC;
}

// ===== K4a: per-chunk local scan (h starts at 0), store end state
// grid (64 chunks, B), 256 thr (lane = d); delta computed on the fly from z half of xp
__global__ __launch_bounds__(256) void k_scan_local(const float* __restrict__ xp,
                                                    const float* __restrict__ Bm,
                                                    const float* __restrict__ A_log,
                                                    float* __restrict__ carry) {
  const int b = blockIdx.y, ch = blockIdx.x, d = threadIdx.x;
  __shared__ __align__(16) float bm[64][16];
  {
    int t = threadIdx.x >> 2, sg = (threadIdx.x & 3) << 2;
    *(float4*)&bm[t][sg] = *(const float4*)&Bm[(b * NPTS + (ch << 6) + t) * 16 + sg];
  }
  float a[16], h[16];
  #pragma unroll
  for (int q = 0; q < 4; ++q) {
    float4 al = *(const float4*)&A_log[(d << 4) + (q << 2)];
    a[(q << 2) + 0] = -expf(al.x);
    a[(q << 2) + 1] = -expf(al.y);
    a[(q << 2) + 2] = -expf(al.z);
    a[(q << 2) + 3] = -expf(al.w);
  }
  #pragma unroll
  for (int s = 0; s < 16; ++s) h[s] = 0.f;
  __syncthreads();
  const int zbase = (b * NPTS + (ch << 6)) * 512 + 256 + d;
  for (int i = 0; i < 64; ++i) {
    float u = sigmoidf_(xp[zbase + (i << 9)]);
    float bb[16];
    #pragma unroll
    for (int q = 0; q < 4; ++q) {
      float4 bv = *(float4*)&bm[i][q << 2];
      bb[(q << 2) + 0] = bv.x; bb[(q << 2) + 1] = bv.y;
      bb[(q << 2) + 2] = bv.z; bb[(q << 2) + 3] = bv.w;
    }
    #pragma unroll
    for (int s = 0; s < 16; ++s) h[s] = fmaf(a[s], h[s], u * bb[s]);
  }
  int cb = ((b * 64 + ch) * 256 + d) << 4;
  #pragma unroll
  for (int q = 0; q < 4; ++q)
    *(float4*)&carry[cb + (q << 2)] =
        make_float4(h[(q << 2) + 0], h[(q << 2) + 1], h[(q << 2) + 2], h[(q << 2) + 3]);
}

// ===== K4b: combine carries across chunks; carry[ch] becomes state BEFORE chunk ch
// 16384 threads, one per (b,d,s); a^64 via 6 squarings
__global__ __launch_bounds__(256) void k_carry(const float* __restrict__ A_log,
                                               float* __restrict__ carry) {
  int g = blockIdx.x * 256 + threadIdx.x;
  int s = g & 15, d = (g >> 4) & 255, b = g >> 12;
  float a = -expf(A_log[(d << 4) + s]);
  float aL = a;
  #pragma unroll
  for (int i = 0; i < 6; ++i) aL *= aL;  // a^64
  float hs = 0.f;
  for (int ch = 0; ch < 64; ++ch) {
    int idx = (((b * 64 + ch) << 8) + d) * 16 + s;
    float tmp = carry[idx];
    carry[idx] = hs;
    hs = fmaf(aL, hs, tmp);
  }
}

// ===== K4c: re-run chunks with true carry-in, emit y[b][t][d] (aliases xs: read-before-write)
__global__ __launch_bounds__(256) void k_scan_y(const float* __restrict__ xp,
                                                const float* __restrict__ xs,
                                                const float* __restrict__ Bm,
                                                const float* __restrict__ Cm,
                                                const float* __restrict__ A_log,
                                                const float* __restrict__ Dskip,
                                                const float* __restrict__ carry,
                                                float* __restrict__ y) {
  const int b = blockIdx.y, ch = blockIdx.x, d = threadIdx.x;
  __shared__ __align__(16) float bm[64][16];
  __shared__ __align__(16) float cm[64][16];
  {
    int t = threadIdx.x >> 2, sg = (threadIdx.x & 3) << 2;
    int row = (b * NPTS + (ch << 6) + t) * 16 + sg;
    *(float4*)&bm[t][sg] = *(const float4*)&Bm[row];
    *(float4*)&cm[t][sg] = *(const float4*)&Cm[row];
  }
  float a[16], h[16];
  #pragma unroll
  for (int q = 0; q < 4; ++q) {
    float4 al = *(const float4*)&A_log[(d << 4) + (q << 2)];
    a[(q << 2) + 0] = -expf(al.x);
    a[(q << 2) + 1] = -expf(al.y);
    a[(q << 2) + 2] = -expf(al.z);
    a[(q << 2) + 3] = -expf(al.w);
  }
  const int cb = ((b * 64 + ch) * 256 + d) << 4;
  #pragma unroll
  for (int q = 0; q < 4; ++q) {
    float4 hv = *(const float4*)&carry[cb + (q << 2)];
    h[(q << 2) + 0] = hv.x; h[(q << 2) + 1] = hv.y;
    h[(q << 2) + 2] = hv.z; h[(q << 2) + 3] = hv.w;
  }
  const float Dv = Dskip[d];
  __syncthreads();
  const int base  = (b * NPTS + (ch << 6)) * 256 + d;
  const int zbase = (b * NPTS + (ch << 6)) * 512 + 256 + d;
  for (int i = 0; i < 64; ++i) {
    float u  = sigmoidf_(xp[zbase + (i << 9)]);
    float xv = xs[base + (i << 8)];
    float bb[16], cc[16];
    #pragma unroll
    for (int q = 0; q < 4; ++q) {
      float4 bv = *(float4*)&bm[i][q << 2];
      float4 cv = *(float4*)&cm[i][q << 2];
      bb[(q << 2) + 0] = bv.x; bb[(q << 2) + 1] = bv.y;
      bb[(q << 2) + 2] = bv.z; bb[(q << 2) + 3] = bv.w;
      cc[(q << 2) + 0] = cv.x; cc[(q << 2) + 1] = cv.y;
      cc[(q << 2) + 2] = cv.z; cc[(q << 2) + 3] = cv.w;
    }
    float yv = Dv * xv;
    #pragma unroll
    for (int s = 0; s < 16; ++s) {
      h[s] = fmaf(a[s], h[s], u * bb[s]);
      yv = fmaf(h[s], cc[s], yv);
    }
    y[base + (i << 8)] = yv;
  }
}

// ===== K5: out_proj GEMM: outpre[b][t][c] = sum_d w_out[c][d]*y[b][t][d] + b_out[c]
__global__ __launch_bounds__(256) void k_outproj(const float* __restrict__ y,
                                                 const float* __restrict__ w,
                                                 const float* __restrict__ bias,
                                                 float* __restrict__ outpre) {
  const int b  = blockIdx.z;
  const int o0 = blockIdx.y << 6;
  const int t0 = blockIdx.x << 6;
  const int tid = threadIdx.x;
  __shared__ __align__(16) float Wl[16][64];
  __shared__ __align__(16) float Xl[16][64];
  const int tx = tid & 15, ty = tid >> 4;
  const int wo = tid >> 2, wk = (tid & 3) << 2;
  const int yt = tid >> 2, ykg = (tid & 3) << 2;
  float acc[4][4] = {};
  for (int k0 = 0; k0 < 256; k0 += 16) {
    __syncthreads();
    float4 wv = *(const float4*)&w[(o0 + wo) * 256 + k0 + wk];
    Wl[wk + 0][wo] = wv.x;
    Wl[wk + 1][wo] = wv.y;
    Wl[wk + 2][wo] = wv.z;
    Wl[wk + 3][wo] = wv.w;
    float4 yv4 = *(const float4*)&y[(b * NPTS + t0 + yt) * 256 + k0 + ykg];
    Xl[ykg + 0][yt] = yv4.x;
    Xl[ykg + 1][yt] = yv4.y;
    Xl[ykg + 2][yt] = yv4.z;
    Xl[ykg + 3][yt] = yv4.w;
    __syncthreads();
    #pragma unroll
    for (int k = 0; k < 16; ++k) {
      float4 av = *(float4*)&Wl[k][ty << 2];
      float4 bv = *(float4*)&Xl[k][tx << 2];
      float aa[4] = {av.x, av.y, av.z, av.w};
      float bb[4] = {bv.x, bv.y, bv.z, bv.w};
      #pragma unroll
      for (int i = 0; i < 4; ++i)
        #pragma unroll
        for (int j = 0; j < 4; ++j)
          acc[i][j] = fmaf(aa[i], bb[j], acc[i][j]);
    }
  }
  float4 bi = *(const float4*)&bias[o0 + (ty << 2)];
  float bia[4] = {bi.x, bi.y, bi.z, bi.w};
  #pragma unroll
  for (int j = 0; j < 4; ++j) {
    int t = t0 + (tx << 2) + j;
    float4 ov = make_float4(acc[0][j] + bia[0], acc[1][j] + bia[1],
                            acc[2][j] + bia[2], acc[3][j] + bia[3]);
    *(float4*)&outpre[(b * NPTS + t) * 256 + o0 + (ty << 2)] = ov;
  }
}

// ===== K6: residual add + LayerNorm over C + transpose to [B][C][N]
// grid (N/32, B), 256 thr = 4 waves; wave = one t-row at a time (8 rows each)
__global__ __launch_bounds__(256) void k_ln(const float* __restrict__ outpre,
                                            const float* __restrict__ x,
                                            const float* __restrict__ gamma,
                                            const float* __restrict__ beta,
                                            float* __restrict__ out) {
  const int b = blockIdx.y, t0 = blockIdx.x << 5;
  const int tid = threadIdx.x, lane = tid & 63, w = tid >> 6;
  __shared__ float xres[256][33];  // residual in, normalized out (stride 33: conflict-free columns)
  #pragma unroll
  for (int r = 0; r < 8; ++r) {
    int lin = (r * 256 + tid) << 2;  // 0..8188 step 4
    int c = lin >> 5, tg = lin & 31;
    float4 xv = *(const float4*)&x[(b * 256 + c) * NPTS + t0 + tg];
    xres[c][tg + 0] = xv.x;
    xres[c][tg + 1] = xv.y;
    xres[c][tg + 2] = xv.z;
    xres[c][tg + 3] = xv.w;
  }
  float g[4], be[4];
  #pragma unroll
  for (int j = 0; j < 4; ++j) {
    g[j] = gamma[lane + 64 * j];
    be[j] = beta[lane + 64 * j];
  }
  __syncthreads();
  for (int rr = 0; rr < 8; ++rr) {
    int trow = w * 8 + rr;
    int rowbase = (b * NPTS + t0 + trow) * 256;
    float v[4];
    float sum = 0.f, sq = 0.f;
    #pragma unroll
    for (int j = 0; j < 4; ++j) {
      int c = lane + 64 * j;
      v[j] = outpre[rowbase + c] + xres[c][trow];
      sum += v[j];
      sq += v[j] * v[j];
    }
    #pragma unroll
    for (int m = 1; m < 64; m <<= 1) {
      sum += __shfl_xor(sum, m);
      sq += __shfl_xor(sq, m);
    }
    float mean = sum * (1.f / 256.f);
    float var = sq * (1.f / 256.f) - mean * mean;
    float rstd = rsqrtf(var + 1e-5f);
    #pragma unroll
    for (int j = 0; j < 4; ++j) {
      int c = lane + 64 * j;
      xres[c][trow] = (v[j] - mean) * rstd * g[j] + be[j];
    }
  }
  __syncthreads();
  #pragma unroll
  for (int p = 0; p < 32; ++p) {
    int c = (p << 3) + (tid >> 5);
    int t = tid & 31;
    out[(b * 256 + c) * NPTS + t0 + t] = xres[c][t];
  }
}

extern "C" void kernel_launch(void* const* d_in, const int* in_sizes, int n_in,
                              void* d_out, int out_size, void* d_ws, size_t ws_size,
                              hipStream_t stream) {
  const float* x     = (const float*)d_in[0];
  const float* w_in  = (const float*)d_in[1];
  const float* b_in  = (const float*)d_in[2];
  const float* wconv = (const float*)d_in[3];
  const float* bconv = (const float*)d_in[4];
  const float* A_log = (const float*)d_in[5];
  const float* Dsk   = (const float*)d_in[6];
  const float* Bw    = (const float*)d_in[7];
  const float* Cw    = (const float*)d_in[8];
  const float* w_out = (const float*)d_in[9];
  const float* b_out = (const float*)d_in[10];
  const float* gamma = (const float*)d_in[11];
  const float* beta  = (const float*)d_in[12];
  float* ws = (float*)d_ws;
  float* xp     = ws + OFF_XP;
  float* xs     = ws + OFF_XS;
  float* Bm     = ws + OFF_BM;
  float* Cm     = ws + OFF_CM;
  float* carry  = ws + OFF_CARRY;
  float* yv     = xs;  // alias: k_scan_y reads xs[t,d] before writing y[t,d] (same thread/iter)
  float* outpre = xp;  // alias: xp dead after k_scan_y
  float* out    = (float*)d_out;

  k_inproj<<<dim3(64, 8, 4), 256, 0, stream>>>(x, w_in, b_in, xp);
  k_conv<<<dim3(64, 4), 256, 0, stream>>>(xp, wconv, bconv, xs);
  k_bc<<<dim3(256, 4), 256, 0, stream>>>(xs, Bw, Cw, Bm, Cm);
  k_scan_local<<<dim3(64, 4), 256, 0, stream>>>(xp, Bm, A_log, carry);
  k_carry<<<64, 256, 0, stream>>>(A_log, carry);
  k_scan_y<<<dim3(64, 4), 256, 0, stream>>>(xp, xs, Bm, Cm, A_log, Dsk, carry, yv);
  k_outproj<<<dim3(64, 4, 4), 256, 0, stream>>>(yv, w_out, b_out, outpre);
  k_ln<<<dim3(128, 4), 256, 0, stream>>>(outpre, x, gamma, beta, out);
}

// Round 2
// 226.007 us; speedup vs baseline: 1.2629x; 1.2629x over previous
//
#include <hip/hip_runtime.h>
#include <math.h>

#define NPTS 4096
#define NB   4

// ---- workspace offsets (floats); total 14,155,776 floats = 56.6 MB ----
// xs region lifecycle: xbf (k_xpose -> k_gemm in_proj) -> xs (k_conv -> k_scan_y) -> outpre (k_gemm out_proj -> k_ln)
// xp region: in_proj out [B][N][512]; x1 half (floats 0..255 of each row) dies after k_conv,
//            reused as bf16 y storage (ushorts 0..255 of each row) written by k_scan_y.
#define OFF_XP    0          // [B][N][512]
#define OFF_XS    8388608    // [B][N][256]
#define OFF_BM    12582912   // [B][N][16]
#define OFF_CM    12845056   // [B][N][16]
#define OFF_CARRY 13107200   // [B][64][256][16]

typedef __bf16 bf16x8 __attribute__((ext_vector_type(8)));
typedef __bf16 bf16x4 __attribute__((ext_vector_type(4)));
typedef float  f32x4  __attribute__((ext_vector_type(4)));

__device__ __forceinline__ float sigmoidf_(float v) { return 1.f / (1.f + expf(-v)); }

// ===== K0: transpose+convert x [B][C][N] fp32 -> xbf [B][N][C] bf16
// grid (N/64, C/64=4, B), 256 thr; LDS bounce, pad 65 (2-way max on scalar ops)
__global__ __launch_bounds__(256) void k_xpose(const float* __restrict__ x,
                                               __bf16* __restrict__ xbf) {
  const int b = blockIdx.z, c0 = blockIdx.y << 6, t0 = blockIdx.x << 6;
  const int tid = threadIdx.x;
  __shared__ float tile[64 * 65];
  #pragma unroll
  for (int r = 0; r < 4; ++r) {
    int cc = (r << 4) + (tid >> 4), tt4 = (tid & 15) << 2;
    float4 v = *(const float4*)&x[((size_t)(b * 256 + c0 + cc)) * NPTS + t0 + tt4];
    tile[cc * 65 + tt4 + 0] = v.x;
    tile[cc * 65 + tt4 + 1] = v.y;
    tile[cc * 65 + tt4 + 2] = v.z;
    tile[cc * 65 + tt4 + 3] = v.w;
  }
  __syncthreads();
  #pragma unroll
  for (int r = 0; r < 4; ++r) {
    int tt = (r << 4) + (tid >> 4), cc4 = (tid & 15) << 2;
    bf16x4 o;
    o[0] = (__bf16)tile[(cc4 + 0) * 65 + tt];
    o[1] = (__bf16)tile[(cc4 + 1) * 65 + tt];
    o[2] = (__bf16)tile[(cc4 + 2) * 65 + tt];
    o[3] = (__bf16)tile[(cc4 + 3) * 65 + tt];
    *(bf16x4*)&xbf[((size_t)(b * NPTS + t0 + tt)) * 256 + c0 + cc4] = o;
  }
}

// ===== K1/K5: bf16 MFMA GEMM: Out[b][t][o] = sum_k W[o][k]*Bop[b][t][k] + bias[o]
// W fp32 [M][256] (converted in staging); Bop bf16 rows (stride bstride ushorts per t-row)
// grid (N/64, M/64, B), 256 thr = 4 waves; 64x64 tile; wave computes 32x32 via 2x2 16x16x32 frags
__global__ __launch_bounds__(256) void k_gemm(const float* __restrict__ W,
                                              const __bf16* __restrict__ Bop, int bstride,
                                              const float* __restrict__ bias,
                                              float* __restrict__ Out, int ostride) {
  const int b = blockIdx.z, o0 = blockIdx.y << 6, t0 = blockIdx.x << 6;
  const int tid = threadIdx.x, lane = tid & 63, wv = tid >> 6;
  const int mo = (wv & 1) << 5, no = (wv >> 1) << 5;
  __shared__ __align__(16) float smem[64 * 68];        // 17.4 KB
  __bf16* Al = (__bf16*)smem;                           // [64][64] bf16, row=o_local, k contig
  __bf16* Bl = Al + 4096;                               // [64][64] bf16, row=t_local, k contig
  float* Cl = smem;                                     // epilogue [64][68] fp32 (overlaps, post-sync)

  f32x4 acc[2][2] = {};
  for (int k0 = 0; k0 < 256; k0 += 64) {
    __syncthreads();
    // stage A (w tile) with fp32->bf16 convert; coalesced float4 along k
    #pragma unroll
    for (int r = 0; r < 4; ++r) {
      int idx = (r << 8) + tid;
      int oo = idx >> 4, kk = (idx & 15) << 2;
      float4 v = *(const float4*)&W[((size_t)(o0 + oo)) * 256 + k0 + kk];
      bf16x4 p;
      p[0] = (__bf16)v.x; p[1] = (__bf16)v.y; p[2] = (__bf16)v.z; p[3] = (__bf16)v.w;
      *(bf16x4*)&Al[oo * 64 + kk] = p;
    }
    // stage B (bf16 rows): 16B vector copies
    #pragma unroll
    for (int r = 0; r < 2; ++r) {
      int idx = (r << 8) + tid;
      int tt = idx >> 3, k8 = (idx & 7) << 3;
      *(uint4*)&Bl[tt * 64 + k8] =
          *(const uint4*)&Bop[((size_t)(b * NPTS + t0 + tt)) * bstride + k0 + k8];
    }
    __syncthreads();
    #pragma unroll
    for (int kc = 0; kc < 64; kc += 32) {
      int kb = kc + ((lane >> 4) << 3);
      bf16x8 a0 = *(bf16x8*)&Al[(mo + (lane & 15)) * 64 + kb];
      bf16x8 a1 = *(bf16x8*)&Al[(mo + 16 + (lane & 15)) * 64 + kb];
      bf16x8 b0 = *(bf16x8*)&Bl[(no + (lane & 15)) * 64 + kb];
      bf16x8 b1 = *(bf16x8*)&Bl[(no + 16 + (lane & 15)) * 64 + kb];
      acc[0][0] = __builtin_amdgcn_mfma_f32_16x16x32_bf16(a0, b0, acc[0][0], 0, 0, 0);
      acc[0][1] = __builtin_amdgcn_mfma_f32_16x16x32_bf16(a0, b1, acc[0][1], 0, 0, 0);
      acc[1][0] = __builtin_amdgcn_mfma_f32_16x16x32_bf16(a1, b0, acc[1][0], 0, 0, 0);
      acc[1][1] = __builtin_amdgcn_mfma_f32_16x16x32_bf16(a1, b1, acc[1][1], 0, 0, 0);
    }
  }
  // epilogue: frags -> LDS [t][o] (pad 68) -> coalesced float4 stores with bias
  __syncthreads();
  #pragma unroll
  for (int mi = 0; mi < 2; ++mi)
    #pragma unroll
    for (int ni = 0; ni < 2; ++ni) {
      int t_loc = no + (ni << 4) + (lane & 15);          // D col = n = t
      int o_b = mo + (mi << 4) + ((lane >> 4) << 2);     // D row = m = o
      #pragma unroll
      for (int rg = 0; rg < 4; ++rg)
        Cl[t_loc * 68 + o_b + rg] = acc[mi][ni][rg];
    }
  __syncthreads();
  #pragma unroll
  for (int r = 0; r < 4; ++r) {
    int tt = (r << 4) + (tid >> 4), oo4 = (tid & 15) << 2;
    float4 v = *(float4*)&Cl[tt * 68 + oo4];
    float4 bi = *(const float4*)&bias[o0 + oo4];
    v.x += bi.x; v.y += bi.y; v.z += bi.z; v.w += bi.w;
    *(float4*)&Out[((size_t)(b * NPTS + t0 + tt)) * ostride + o0 + oo4] = v;
  }
}

// ===== K2: depthwise causal conv (w=4) + bias + silu -> xs[b][t][d]
__global__ __launch_bounds__(256) void k_conv(const float* __restrict__ xp,
                                              const float* __restrict__ wconv,
                                              const float* __restrict__ bconv,
                                              float* __restrict__ xs) {
  const int b = blockIdx.y, t0 = blockIdx.x << 6, d = threadIdx.x;
  const float4 wc = *(const float4*)&wconv[d << 2];
  const float bc = bconv[d];
  float xm3 = 0.f, xm2 = 0.f, xm1 = 0.f;
  if (t0 > 0) {
    int bb = (b * NPTS + t0) * 512 + d;
    xm3 = xp[bb - 3 * 512];
    xm2 = xp[bb - 2 * 512];
    xm1 = xp[bb - 1 * 512];
  }
  for (int i = 0; i < 64; ++i) {
    int t = t0 + i;
    float xc = xp[(b * NPTS + t) * 512 + d];
    float cv = fmaf(wc.x, xm3, fmaf(wc.y, xm2, fmaf(wc.z, xm1, fmaf(wc.w, xc, bc))));
    xs[(b * NPTS + t) * 256 + d] = cv * sigmoidf_(cv);
    xm3 = xm2; xm2 = xm1; xm1 = xc;
  }
}

// ===== K3: Bm[b][t][s] = sum_d xs[b][t][d]*Bw[s][d];  Cm likewise
__global__ __launch_bounds__(256) void k_bc(const float* __restrict__ xs,
                                            const float* __restrict__ Bw,
                                            const float* __restrict__ Cw,
                                            float* __restrict__ Bm,
                                            float* __restrict__ Cm) {
  const int b = blockIdx.y, t0 = blockIdx.x << 4, tid = threadIdx.x;
  __shared__ __align__(16) float xt[16][256];
  __shared__ __align__(16) float Bl[16][260];
  __shared__ __align__(16) float Cl[16][260];
  #pragma unroll
  for (int r = 0; r < 4; ++r) {
    int lin = (r * 256 + tid) << 2;
    int t = lin >> 8, dd = lin & 255;
    *(float4*)&xt[t][dd] = *(const float4*)&xs[(b * NPTS + t0 + t) * 256 + dd];
    int idx = r * 256 + tid;
    int s = idx >> 6, dg = (idx & 63) << 2;
    *(float4*)&Bl[s][dg] = *(const float4*)&Bw[s * 256 + dg];
    *(float4*)&Cl[s][dg] = *(const float4*)&Cw[s * 256 + dg];
  }
  __syncthreads();
  const int s = tid & 15, tl = tid >> 4;
  float accB = 0.f, accC = 0.f;
  #pragma unroll 8
  for (int dd = 0; dd < 256; dd += 4) {
    float4 xv = *(float4*)&xt[tl][dd];
    float4 bv = *(float4*)&Bl[s][dd];
    float4 cv = *(float4*)&Cl[s][dd];
    accB += xv.x * bv.x + xv.y * bv.y + xv.z * bv.z + xv.w * bv.w;
    accC += xv.x * cv.x + xv.y * cv.y + xv.z * cv.z + xv.w * cv.w;
  }
  int row = (b * NPTS + t0 + tl) * 16 + s;
  Bm[row] = accB;
  Cm[row] = accC;
}

// ===== K4a: per-chunk local scan (h starts at 0), store end state
__global__ __launch_bounds__(256) void k_scan_local(const float* __restrict__ xp,
                                                    const float* __restrict__ Bm,
                                                    const float* __restrict__ A_log,
                                                    float* __restrict__ carry) {
  const int b = blockIdx.y, ch = blockIdx.x, d = threadIdx.x;
  __shared__ __align__(16) float bm[64][16];
  {
    int t = threadIdx.x >> 2, sg = (threadIdx.x & 3) << 2;
    *(float4*)&bm[t][sg] = *(const float4*)&Bm[(b * NPTS + (ch << 6) + t) * 16 + sg];
  }
  float a[16], h[16];
  #pragma unroll
  for (int q = 0; q < 4; ++q) {
    float4 al = *(const float4*)&A_log[(d << 4) + (q << 2)];
    a[(q << 2) + 0] = -expf(al.x);
    a[(q << 2) + 1] = -expf(al.y);
    a[(q << 2) + 2] = -expf(al.z);
    a[(q << 2) + 3] = -expf(al.w);
  }
  #pragma unroll
  for (int s = 0; s < 16; ++s) h[s] = 0.f;
  __syncthreads();
  const int zbase = (b * NPTS + (ch << 6)) * 512 + 256 + d;
  for (int i = 0; i < 64; ++i) {
    float u = sigmoidf_(xp[zbase + (i << 9)]);
    float bb[16];
    #pragma unroll
    for (int q = 0; q < 4; ++q) {
      float4 bv = *(float4*)&bm[i][q << 2];
      bb[(q << 2) + 0] = bv.x; bb[(q << 2) + 1] = bv.y;
      bb[(q << 2) + 2] = bv.z; bb[(q << 2) + 3] = bv.w;
    }
    #pragma unroll
    for (int s = 0; s < 16; ++s) h[s] = fmaf(a[s], h[s], u * bb[s]);
  }
  int cb = ((b * 64 + ch) * 256 + d) << 4;
  #pragma unroll
  for (int q = 0; q < 4; ++q)
    *(float4*)&carry[cb + (q << 2)] =
        make_float4(h[(q << 2) + 0], h[(q << 2) + 1], h[(q << 2) + 2], h[(q << 2) + 3]);
}

// ===== K4b: combine carries across chunks; carry[ch] becomes state BEFORE chunk ch
__global__ __launch_bounds__(256) void k_carry(const float* __restrict__ A_log,
                                               float* __restrict__ carry) {
  int g = blockIdx.x * 256 + threadIdx.x;
  int s = g & 15, d = (g >> 4) & 255, b = g >> 12;
  float a = -expf(A_log[(d << 4) + s]);
  float aL = a;
  #pragma unroll
  for (int i = 0; i < 6; ++i) aL *= aL;  // a^64
  float hs = 0.f;
  for (int ch = 0; ch < 64; ++ch) {
    int idx = (((b * 64 + ch) << 8) + d) * 16 + s;
    float tmp = carry[idx];
    carry[idx] = hs;
    hs = fmaf(aL, hs, tmp);
  }
}

// ===== K4c: re-run chunks with true carry-in, emit y as bf16 into dead x1 half of xp rows
__global__ __launch_bounds__(256) void k_scan_y(const float* __restrict__ xp,
                                                const float* __restrict__ xs,
                                                const float* __restrict__ Bm,
                                                const float* __restrict__ Cm,
                                                const float* __restrict__ A_log,
                                                const float* __restrict__ Dskip,
                                                const float* __restrict__ carry,
                                                __bf16* __restrict__ ybf) {
  const int b = blockIdx.y, ch = blockIdx.x, d = threadIdx.x;
  __shared__ __align__(16) float bm[64][16];
  __shared__ __align__(16) float cm[64][16];
  {
    int t = threadIdx.x >> 2, sg = (threadIdx.x & 3) << 2;
    int row = (b * NPTS + (ch << 6) + t) * 16 + sg;
    *(float4*)&bm[t][sg] = *(const float4*)&Bm[row];
    *(float4*)&cm[t][sg] = *(const float4*)&Cm[row];
  }
  float a[16], h[16];
  #pragma unroll
  for (int q = 0; q < 4; ++q) {
    float4 al = *(const float4*)&A_log[(d << 4) + (q << 2)];
    a[(q << 2) + 0] = -expf(al.x);
    a[(q << 2) + 1] = -expf(al.y);
    a[(q << 2) + 2] = -expf(al.z);
    a[(q << 2) + 3] = -expf(al.w);
  }
  const int cb = ((b * 64 + ch) * 256 + d) << 4;
  #pragma unroll
  for (int q = 0; q < 4; ++q) {
    float4 hv = *(const float4*)&carry[cb + (q << 2)];
    h[(q << 2) + 0] = hv.x; h[(q << 2) + 1] = hv.y;
    h[(q << 2) + 2] = hv.z; h[(q << 2) + 3] = hv.w;
  }
  const float Dv = Dskip[d];
  __syncthreads();
  const int base  = (b * NPTS + (ch << 6)) * 256 + d;
  const int zbase = (b * NPTS + (ch << 6)) * 512 + 256 + d;
  const size_t ybase = ((size_t)(b * NPTS + (ch << 6))) * 1024 + d;  // bf16 units inside xp rows
  for (int i = 0; i < 64; ++i) {
    float u  = sigmoidf_(xp[zbase + (i << 9)]);
    float xv = xs[base + (i << 8)];
    float bb[16], cc[16];
    #pragma unroll
    for (int q = 0; q < 4; ++q) {
      float4 bv = *(float4*)&bm[i][q << 2];
      float4 cv = *(float4*)&cm[i][q << 2];
      bb[(q << 2) + 0] = bv.x; bb[(q << 2) + 1] = bv.y;
      bb[(q << 2) + 2] = bv.z; bb[(q << 2) + 3] = bv.w;
      cc[(q << 2) + 0] = cv.x; cc[(q << 2) + 1] = cv.y;
      cc[(q << 2) + 2] = cv.z; cc[(q << 2) + 3] = cv.w;
    }
    float yv = Dv * xv;
    #pragma unroll
    for (int s = 0; s < 16; ++s) {
      h[s] = fmaf(a[s], h[s], u * bb[s]);
      yv = fmaf(h[s], cc[s], yv);
    }
    ybf[ybase + ((size_t)i << 10)] = (__bf16)yv;
  }
}

// ===== K6: residual add + LayerNorm over C + transpose to [B][C][N]
__global__ __launch_bounds__(256) void k_ln(const float* __restrict__ outpre,
                                            const float* __restrict__ x,
                                            const float* __restrict__ gamma,
                                            const float* __restrict__ beta,
                                            float* __restrict__ out) {
  const int b = blockIdx.y, t0 = blockIdx.x << 5;
  const int tid = threadIdx.x, lane = tid & 63, w = tid >> 6;
  __shared__ float xres[256][33];
  #pragma unroll
  for (int r = 0; r < 8; ++r) {
    int lin = (r * 256 + tid) << 2;
    int c = lin >> 5, tg = lin & 31;
    float4 xv = *(const float4*)&x[(b * 256 + c) * NPTS + t0 + tg];
    xres[c][tg + 0] = xv.x;
    xres[c][tg + 1] = xv.y;
    xres[c][tg + 2] = xv.z;
    xres[c][tg + 3] = xv.w;
  }
  float g[4], be[4];
  #pragma unroll
  for (int j = 0; j < 4; ++j) {
    g[j] = gamma[lane + 64 * j];
    be[j] = beta[lane + 64 * j];
  }
  __syncthreads();
  for (int rr = 0; rr < 8; ++rr) {
    int trow = w * 8 + rr;
    int rowbase = (b * NPTS + t0 + trow) * 256;
    float v[4];
    float sum = 0.f, sq = 0.f;
    #pragma unroll
    for (int j = 0; j < 4; ++j) {
      int c = lane + 64 * j;
      v[j] = outpre[rowbase + c] + xres[c][trow];
      sum += v[j];
      sq += v[j] * v[j];
    }
    #pragma unroll
    for (int m = 1; m < 64; m <<= 1) {
      sum += __shfl_xor(sum, m);
      sq += __shfl_xor(sq, m);
    }
    float mean = sum * (1.f / 256.f);
    float var = sq * (1.f / 256.f) - mean * mean;
    float rstd = rsqrtf(var + 1e-5f);
    #pragma unroll
    for (int j = 0; j < 4; ++j) {
      int c = lane + 64 * j;
      xres[c][trow] = (v[j] - mean) * rstd * g[j] + be[j];
    }
  }
  __syncthreads();
  #pragma unroll
  for (int p = 0; p < 32; ++p) {
    int c = (p << 3) + (tid >> 5);
    int t = tid & 31;
    out[(b * 256 + c) * NPTS + t0 + t] = xres[c][t];
  }
}

extern "C" void kernel_launch(void* const* d_in, const int* in_sizes, int n_in,
                              void* d_out, int out_size, void* d_ws, size_t ws_size,
                              hipStream_t stream) {
  const float* x     = (const float*)d_in[0];
  const float* w_in  = (const float*)d_in[1];
  const float* b_in  = (const float*)d_in[2];
  const float* wconv = (const float*)d_in[3];
  const float* bconv = (const float*)d_in[4];
  const float* A_log = (const float*)d_in[5];
  const float* Dsk   = (const float*)d_in[6];
  const float* Bw    = (const float*)d_in[7];
  const float* Cw    = (const float*)d_in[8];
  const float* w_out = (const float*)d_in[9];
  const float* b_out = (const float*)d_in[10];
  const float* gamma = (const float*)d_in[11];
  const float* beta  = (const float*)d_in[12];
  float* ws = (float*)d_ws;
  float* xp     = ws + OFF_XP;
  float* xs     = ws + OFF_XS;
  float* Bm     = ws + OFF_BM;
  float* Cm     = ws + OFF_CM;
  float* carry  = ws + OFF_CARRY;
  __bf16* xbf   = (__bf16*)xs;   // xs region: xbf until in_proj done, then xs, then outpre
  __bf16* ybf   = (__bf16*)xp;   // bf16 y lives in dead x1 half of xp rows (first 256 ushorts/row)
  float* outpre = xs;            // xs region reused after scan_y
  float* out    = (float*)d_out;

  k_xpose<<<dim3(64, 4, 4), 256, 0, stream>>>(x, xbf);
  k_gemm<<<dim3(64, 8, 4), 256, 0, stream>>>(w_in, xbf, 256, b_in, xp, 512);
  k_conv<<<dim3(64, 4), 256, 0, stream>>>(xp, wconv, bconv, xs);
  k_bc<<<dim3(256, 4), 256, 0, stream>>>(xs, Bw, Cw, Bm, Cm);
  k_scan_local<<<dim3(64, 4), 256, 0, stream>>>(xp, Bm, A_log, carry);
  k_carry<<<64, 256, 0, stream>>>(A_log, carry);
  k_scan_y<<<dim3(64, 4), 256, 0, stream>>>(xp, xs, Bm, Cm, A_log, Dsk, carry, ybf);
  k_gemm<<<dim3(64, 4, 4), 256, 0, stream>>>(w_out, ybf, 1024, b_out, outpre, 256);
  k_ln<<<dim3(128, 4), 256, 0, stream>>>(outpre, x, gamma, beta, out);
}

// Round 3
// 191.853 us; speedup vs baseline: 1.4877x; 1.1780x over previous
//
#include <hip/hip_runtime.h>
#include <math.h>

#define NPTS 4096
#define NB   4
#define NCH  128   // scan chunks
#define CHL  32    // chunk length (NCH*CHL == NPTS)

// ---- workspace offsets (floats); total 15,204,352 floats = 60.8 MB ----
// xs region lifecycle: xbf (k_xpose -> in_proj gemm) -> xs (k_conv -> k_scan_y) -> outpre (out_proj gemm -> k_ln)
// xp region: in_proj out [B][N][512]; x1 half (floats 0..255 of each row) dies after k_conv,
//            reused as bf16 y storage (ushorts 0..255 of each row) written by k_scan_y.
#define OFF_XP    0          // [B][N][512]
#define OFF_XS    8388608    // [B][N][256]
#define OFF_BM    12582912   // [B][N][16]
#define OFF_CM    12845056   // [B][N][16]
#define OFF_CARRY 13107200   // [B][NCH][256][16]

typedef __bf16 bf16x8 __attribute__((ext_vector_type(8)));
typedef __bf16 bf16x4 __attribute__((ext_vector_type(4)));
typedef float  f32x4  __attribute__((ext_vector_type(4)));

__device__ __forceinline__ float sigmoidf_(float v) { return 1.f / (1.f + expf(-v)); }

// ===== K0: transpose+convert x [B][C][N] fp32 -> xbf [B][N][C] bf16
__global__ __launch_bounds__(256) void k_xpose(const float* __restrict__ x,
                                               __bf16* __restrict__ xbf) {
  const int b = blockIdx.z, c0 = blockIdx.y << 6, t0 = blockIdx.x << 6;
  const int tid = threadIdx.x;
  __shared__ float tile[64 * 65];
  #pragma unroll
  for (int r = 0; r < 4; ++r) {
    int cc = (r << 4) + (tid >> 4), tt4 = (tid & 15) << 2;
    float4 v = *(const float4*)&x[((size_t)(b * 256 + c0 + cc)) * NPTS + t0 + tt4];
    tile[cc * 65 + tt4 + 0] = v.x;
    tile[cc * 65 + tt4 + 1] = v.y;
    tile[cc * 65 + tt4 + 2] = v.z;
    tile[cc * 65 + tt4 + 3] = v.w;
  }
  __syncthreads();
  #pragma unroll
  for (int r = 0; r < 4; ++r) {
    int tt = (r << 4) + (tid >> 4), cc4 = (tid & 15) << 2;
    bf16x4 o;
    o[0] = (__bf16)tile[(cc4 + 0) * 65 + tt];
    o[1] = (__bf16)tile[(cc4 + 1) * 65 + tt];
    o[2] = (__bf16)tile[(cc4 + 2) * 65 + tt];
    o[3] = (__bf16)tile[(cc4 + 3) * 65 + tt];
    *(bf16x4*)&xbf[((size_t)(b * NPTS + t0 + tt)) * 256 + c0 + cc4] = o;
  }
}

// ===== bf16 MFMA GEMM: Out[b][t][o] = sum_k W[o][k]*Bop[b][t][k] + bias[o]
__global__ __launch_bounds__(256) void k_gemm(const float* __restrict__ W,
                                              const __bf16* __restrict__ Bop, int bstride,
                                              const float* __restrict__ bias,
                                              float* __restrict__ Out, int ostride) {
  const int b = blockIdx.z, o0 = blockIdx.y << 6, t0 = blockIdx.x << 6;
  const int tid = threadIdx.x, lane = tid & 63, wv = tid >> 6;
  const int mo = (wv & 1) << 5, no = (wv >> 1) << 5;
  __shared__ __align__(16) float smem[64 * 68];
  __bf16* Al = (__bf16*)smem;
  __bf16* Bl = Al + 4096;
  float* Cl = smem;

  f32x4 acc[2][2] = {};
  for (int k0 = 0; k0 < 256; k0 += 64) {
    __syncthreads();
    #pragma unroll
    for (int r = 0; r < 4; ++r) {
      int idx = (r << 8) + tid;
      int oo = idx >> 4, kk = (idx & 15) << 2;
      float4 v = *(const float4*)&W[((size_t)(o0 + oo)) * 256 + k0 + kk];
      bf16x4 p;
      p[0] = (__bf16)v.x; p[1] = (__bf16)v.y; p[2] = (__bf16)v.z; p[3] = (__bf16)v.w;
      *(bf16x4*)&Al[oo * 64 + kk] = p;
    }
    #pragma unroll
    for (int r = 0; r < 2; ++r) {
      int idx = (r << 8) + tid;
      int tt = idx >> 3, k8 = (idx & 7) << 3;
      *(uint4*)&Bl[tt * 64 + k8] =
          *(const uint4*)&Bop[((size_t)(b * NPTS + t0 + tt)) * bstride + k0 + k8];
    }
    __syncthreads();
    #pragma unroll
    for (int kc = 0; kc < 64; kc += 32) {
      int kb = kc + ((lane >> 4) << 3);
      bf16x8 a0 = *(bf16x8*)&Al[(mo + (lane & 15)) * 64 + kb];
      bf16x8 a1 = *(bf16x8*)&Al[(mo + 16 + (lane & 15)) * 64 + kb];
      bf16x8 b0 = *(bf16x8*)&Bl[(no + (lane & 15)) * 64 + kb];
      bf16x8 b1 = *(bf16x8*)&Bl[(no + 16 + (lane & 15)) * 64 + kb];
      acc[0][0] = __builtin_amdgcn_mfma_f32_16x16x32_bf16(a0, b0, acc[0][0], 0, 0, 0);
      acc[0][1] = __builtin_amdgcn_mfma_f32_16x16x32_bf16(a0, b1, acc[0][1], 0, 0, 0);
      acc[1][0] = __builtin_amdgcn_mfma_f32_16x16x32_bf16(a1, b0, acc[1][0], 0, 0, 0);
      acc[1][1] = __builtin_amdgcn_mfma_f32_16x16x32_bf16(a1, b1, acc[1][1], 0, 0, 0);
    }
  }
  __syncthreads();
  #pragma unroll
  for (int mi = 0; mi < 2; ++mi)
    #pragma unroll
    for (int ni = 0; ni < 2; ++ni) {
      int t_loc = no + (ni << 4) + (lane & 15);
      int o_b = mo + (mi << 4) + ((lane >> 4) << 2);
      #pragma unroll
      for (int rg = 0; rg < 4; ++rg)
        Cl[t_loc * 68 + o_b + rg] = acc[mi][ni][rg];
    }
  __syncthreads();
  #pragma unroll
  for (int r = 0; r < 4; ++r) {
    int tt = (r << 4) + (tid >> 4), oo4 = (tid & 15) << 2;
    float4 v = *(float4*)&Cl[tt * 68 + oo4];
    float4 bi = *(const float4*)&bias[o0 + oo4];
    v.x += bi.x; v.y += bi.y; v.z += bi.z; v.w += bi.w;
    *(float4*)&Out[((size_t)(b * NPTS + t0 + tt)) * ostride + o0 + oo4] = v;
  }
}

// ===== K2: depthwise causal conv (w=4) + bias + silu -> xs[b][t][d]
// grid (N/16, B): 1024 blocks for TLP; 16 t per block
__global__ __launch_bounds__(256) void k_conv(const float* __restrict__ xp,
                                              const float* __restrict__ wconv,
                                              const float* __restrict__ bconv,
                                              float* __restrict__ xs) {
  const int b = blockIdx.y, t0 = blockIdx.x << 4, d = threadIdx.x;
  const float4 wc = *(const float4*)&wconv[d << 2];
  const float bc = bconv[d];
  float xm3 = 0.f, xm2 = 0.f, xm1 = 0.f;
  if (t0 > 0) {
    int bb = (b * NPTS + t0) * 512 + d;
    xm3 = xp[bb - 3 * 512];
    xm2 = xp[bb - 2 * 512];
    xm1 = xp[bb - 1 * 512];
  }
  #pragma unroll
  for (int i = 0; i < 16; ++i) {
    int t = t0 + i;
    float xc = xp[(b * NPTS + t) * 512 + d];
    float cv = fmaf(wc.x, xm3, fmaf(wc.y, xm2, fmaf(wc.z, xm1, fmaf(wc.w, xc, bc))));
    xs[(b * NPTS + t) * 256 + d] = cv * sigmoidf_(cv);
    xm3 = xm2; xm2 = xm1; xm1 = xc;
  }
}

// ===== K3: Bm[b][t][s] = sum_d xs[b][t][d]*Bw[s][d];  Cm likewise
__global__ __launch_bounds__(256) void k_bc(const float* __restrict__ xs,
                                            const float* __restrict__ Bw,
                                            const float* __restrict__ Cw,
                                            float* __restrict__ Bm,
                                            float* __restrict__ Cm) {
  const int b = blockIdx.y, t0 = blockIdx.x << 4, tid = threadIdx.x;
  __shared__ __align__(16) float xt[16][256];
  __shared__ __align__(16) float Bl[16][260];
  __shared__ __align__(16) float Cl[16][260];
  #pragma unroll
  for (int r = 0; r < 4; ++r) {
    int lin = (r * 256 + tid) << 2;
    int t = lin >> 8, dd = lin & 255;
    *(float4*)&xt[t][dd] = *(const float4*)&xs[(b * NPTS + t0 + t) * 256 + dd];
    int idx = r * 256 + tid;
    int s = idx >> 6, dg = (idx & 63) << 2;
    *(float4*)&Bl[s][dg] = *(const float4*)&Bw[s * 256 + dg];
    *(float4*)&Cl[s][dg] = *(const float4*)&Cw[s * 256 + dg];
  }
  __syncthreads();
  const int s = tid & 15, tl = tid >> 4;
  float accB = 0.f, accC = 0.f;
  #pragma unroll 8
  for (int dd = 0; dd < 256; dd += 4) {
    float4 xv = *(float4*)&xt[tl][dd];
    float4 bv = *(float4*)&Bl[s][dd];
    float4 cv = *(float4*)&Cl[s][dd];
    accB += xv.x * bv.x + xv.y * bv.y + xv.z * bv.z + xv.w * bv.w;
    accC += xv.x * cv.x + xv.y * cv.y + xv.z * cv.z + xv.w * cv.w;
  }
  int row = (b * NPTS + t0 + tl) * 16 + s;
  Bm[row] = accB;
  Cm[row] = accC;
}

// ===== K4a: per-chunk local scan (h=0 start), store end state
// 512 thr: lane pair per d (8 states each); grid (NCH, B)
__global__ __launch_bounds__(512) void k_scan_local(const float* __restrict__ xp,
                                                    const float* __restrict__ Bm,
                                                    const float* __restrict__ A_log,
                                                    float* __restrict__ carry) {
  const int b = blockIdx.y, ch = blockIdx.x;
  const int tid = threadIdx.x;
  const int d = tid >> 1, sh = (tid & 1) << 3;  // state offset 0 or 8
  __shared__ __align__(16) float bm[CHL][16];
  {
    int t = tid >> 4, s = tid & 15;
    bm[t][s] = Bm[(b * NPTS + (ch << 5) + t) * 16 + s];
  }
  float a[8], h[8];
  {
    float4 a0 = *(const float4*)&A_log[(d << 4) + sh];
    float4 a1 = *(const float4*)&A_log[(d << 4) + sh + 4];
    a[0] = -expf(a0.x); a[1] = -expf(a0.y); a[2] = -expf(a0.z); a[3] = -expf(a0.w);
    a[4] = -expf(a1.x); a[5] = -expf(a1.y); a[6] = -expf(a1.z); a[7] = -expf(a1.w);
  }
  #pragma unroll
  for (int s = 0; s < 8; ++s) h[s] = 0.f;
  __syncthreads();
  const size_t zbase = ((size_t)(b * NPTS + (ch << 5))) * 512 + 256 + d;
  float zn[4];
  #pragma unroll
  for (int k = 0; k < 4; ++k) zn[k] = xp[zbase + ((size_t)k << 9)];
  for (int g = 0; g < CHL / 4; ++g) {
    float zc[4];
    #pragma unroll
    for (int k = 0; k < 4; ++k) zc[k] = zn[k];
    if (g < CHL / 4 - 1) {
      #pragma unroll
      for (int k = 0; k < 4; ++k) zn[k] = xp[zbase + ((size_t)((g + 1) * 4 + k) << 9)];
    }
    #pragma unroll
    for (int k = 0; k < 4; ++k) {
      int i = g * 4 + k;
      float u = sigmoidf_(zc[k]);
      float4 b0 = *(float4*)&bm[i][sh];
      float4 b1 = *(float4*)&bm[i][sh + 4];
      h[0] = fmaf(a[0], h[0], u * b0.x);
      h[1] = fmaf(a[1], h[1], u * b0.y);
      h[2] = fmaf(a[2], h[2], u * b0.z);
      h[3] = fmaf(a[3], h[3], u * b0.w);
      h[4] = fmaf(a[4], h[4], u * b1.x);
      h[5] = fmaf(a[5], h[5], u * b1.y);
      h[6] = fmaf(a[6], h[6], u * b1.z);
      h[7] = fmaf(a[7], h[7], u * b1.w);
    }
  }
  int cb = (((b * NCH + ch) << 8) + d) * 16 + sh;
  *(float4*)&carry[cb]     = make_float4(h[0], h[1], h[2], h[3]);
  *(float4*)&carry[cb + 4] = make_float4(h[4], h[5], h[6], h[7]);
}

// ===== K4b: combine carries; carry[ch] becomes state BEFORE chunk ch
__global__ __launch_bounds__(256) void k_carry(const float* __restrict__ A_log,
                                               float* __restrict__ carry) {
  int g = blockIdx.x * 256 + threadIdx.x;
  int s = g & 15, d = (g >> 4) & 255, b = g >> 12;
  float a = -expf(A_log[(d << 4) + s]);
  float aL = a;
  #pragma unroll
  for (int i = 0; i < 5; ++i) aL *= aL;  // a^32
  float hs = 0.f;
  for (int ch = 0; ch < NCH; ++ch) {
    int idx = (((b * NCH + ch) << 8) + d) * 16 + s;
    float tmp = carry[idx];
    carry[idx] = hs;
    hs = fmaf(aL, hs, tmp);
  }
}

// ===== K4c: re-run chunks with true carry-in, emit y bf16 into dead x1 half of xp rows
// 512 thr: lane pair per d; y partial dots combined via shfl_xor(1)
__global__ __launch_bounds__(512) void k_scan_y(const float* __restrict__ xp,
                                                const float* __restrict__ xs,
                                                const float* __restrict__ Bm,
                                                const float* __restrict__ Cm,
                                                const float* __restrict__ A_log,
                                                const float* __restrict__ Dskip,
                                                const float* __restrict__ carry,
                                                __bf16* __restrict__ ybf) {
  const int b = blockIdx.y, ch = blockIdx.x;
  const int tid = threadIdx.x;
  const int d = tid >> 1, sh = (tid & 1) << 3;
  __shared__ __align__(16) float bm[CHL][16];
  __shared__ __align__(16) float cm[CHL][16];
  {
    int rowbase = (b * NPTS + (ch << 5)) * 16;
    bm[0][tid] = Bm[rowbase + tid];   // [CHL][16] is 512 contiguous floats
    cm[0][tid] = Cm[rowbase + tid];
  }
  float a[8], h[8];
  {
    float4 a0 = *(const float4*)&A_log[(d << 4) + sh];
    float4 a1 = *(const float4*)&A_log[(d << 4) + sh + 4];
    a[0] = -expf(a0.x); a[1] = -expf(a0.y); a[2] = -expf(a0.z); a[3] = -expf(a0.w);
    a[4] = -expf(a1.x); a[5] = -expf(a1.y); a[6] = -expf(a1.z); a[7] = -expf(a1.w);
  }
  {
    int cb = (((b * NCH + ch) << 8) + d) * 16 + sh;
    float4 h0 = *(const float4*)&carry[cb];
    float4 h1 = *(const float4*)&carry[cb + 4];
    h[0] = h0.x; h[1] = h0.y; h[2] = h0.z; h[3] = h0.w;
    h[4] = h1.x; h[5] = h1.y; h[6] = h1.z; h[7] = h1.w;
  }
  const float Dv = Dskip[d];
  __syncthreads();
  const size_t base  = ((size_t)(b * NPTS + (ch << 5))) * 256 + d;
  const size_t zbase = ((size_t)(b * NPTS + (ch << 5))) * 512 + 256 + d;
  const size_t ybase = ((size_t)(b * NPTS + (ch << 5))) * 1024 + d;
  float zn[4], xn[4];
  #pragma unroll
  for (int k = 0; k < 4; ++k) {
    zn[k] = xp[zbase + ((size_t)k << 9)];
    xn[k] = xs[base + ((size_t)k << 8)];
  }
  for (int g = 0; g < CHL / 4; ++g) {
    float zc[4], xc[4];
    #pragma unroll
    for (int k = 0; k < 4; ++k) { zc[k] = zn[k]; xc[k] = xn[k]; }
    if (g < CHL / 4 - 1) {
      #pragma unroll
      for (int k = 0; k < 4; ++k) {
        zn[k] = xp[zbase + ((size_t)((g + 1) * 4 + k) << 9)];
        xn[k] = xs[base + ((size_t)((g + 1) * 4 + k) << 8)];
      }
    }
    #pragma unroll
    for (int k = 0; k < 4; ++k) {
      int i = g * 4 + k;
      float u = sigmoidf_(zc[k]);
      float4 b0 = *(float4*)&bm[i][sh];
      float4 b1 = *(float4*)&bm[i][sh + 4];
      float4 c0 = *(float4*)&cm[i][sh];
      float4 c1 = *(float4*)&cm[i][sh + 4];
      h[0] = fmaf(a[0], h[0], u * b0.x);
      h[1] = fmaf(a[1], h[1], u * b0.y);
      h[2] = fmaf(a[2], h[2], u * b0.z);
      h[3] = fmaf(a[3], h[3], u * b0.w);
      h[4] = fmaf(a[4], h[4], u * b1.x);
      h[5] = fmaf(a[5], h[5], u * b1.y);
      h[6] = fmaf(a[6], h[6], u * b1.z);
      h[7] = fmaf(a[7], h[7], u * b1.w);
      float yv = h[0] * c0.x + h[1] * c0.y + h[2] * c0.z + h[3] * c0.w
               + h[4] * c1.x + h[5] * c1.y + h[6] * c1.z + h[7] * c1.w;
      yv += __shfl_xor(yv, 1);
      if ((tid & 1) == 0)
        ybf[ybase + ((size_t)i << 10)] = (__bf16)fmaf(Dv, xc[k], yv);
    }
  }
}

// ===== K6: residual add + LayerNorm over C + transpose to [B][C][N]
__global__ __launch_bounds__(256) void k_ln(const float* __restrict__ outpre,
                                            const float* __restrict__ x,
                                            const float* __restrict__ gamma,
                                            const float* __restrict__ beta,
                                            float* __restrict__ out) {
  const int b = blockIdx.y, t0 = blockIdx.x << 5;
  const int tid = threadIdx.x, lane = tid & 63, w = tid >> 6;
  __shared__ float xres[256][33];
  #pragma unroll
  for (int r = 0; r < 8; ++r) {
    int lin = (r * 256 + tid) << 2;
    int c = lin >> 5, tg = lin & 31;
    float4 xv = *(const float4*)&x[(b * 256 + c) * NPTS + t0 + tg];
    xres[c][tg + 0] = xv.x;
    xres[c][tg + 1] = xv.y;
    xres[c][tg + 2] = xv.z;
    xres[c][tg + 3] = xv.w;
  }
  float g[4], be[4];
  #pragma unroll
  for (int j = 0; j < 4; ++j) {
    g[j] = gamma[lane + 64 * j];
    be[j] = beta[lane + 64 * j];
  }
  __syncthreads();
  for (int rr = 0; rr < 8; ++rr) {
    int trow = w * 8 + rr;
    int rowbase = (b * NPTS + t0 + trow) * 256;
    float v[4];
    float sum = 0.f, sq = 0.f;
    #pragma unroll
    for (int j = 0; j < 4; ++j) {
      int c = lane + 64 * j;
      v[j] = outpre[rowbase + c] + xres[c][trow];
      sum += v[j];
      sq += v[j] * v[j];
    }
    #pragma unroll
    for (int m = 1; m < 64; m <<= 1) {
      sum += __shfl_xor(sum, m);
      sq += __shfl_xor(sq, m);
    }
    float mean = sum * (1.f / 256.f);
    float var = sq * (1.f / 256.f) - mean * mean;
    float rstd = rsqrtf(var + 1e-5f);
    #pragma unroll
    for (int j = 0; j < 4; ++j) {
      int c = lane + 64 * j;
      xres[c][trow] = (v[j] - mean) * rstd * g[j] + be[j];
    }
  }
  __syncthreads();
  #pragma unroll
  for (int p = 0; p < 32; ++p) {
    int c = (p << 3) + (tid >> 5);
    int t = tid & 31;
    out[(b * 256 + c) * NPTS + t0 + t] = xres[c][t];
  }
}

extern "C" void kernel_launch(void* const* d_in, const int* in_sizes, int n_in,
                              void* d_out, int out_size, void* d_ws, size_t ws_size,
                              hipStream_t stream) {
  const float* x     = (const float*)d_in[0];
  const float* w_in  = (const float*)d_in[1];
  const float* b_in  = (const float*)d_in[2];
  const float* wconv = (const float*)d_in[3];
  const float* bconv = (const float*)d_in[4];
  const float* A_log = (const float*)d_in[5];
  const float* Dsk   = (const float*)d_in[6];
  const float* Bw    = (const float*)d_in[7];
  const float* Cw    = (const float*)d_in[8];
  const float* w_out = (const float*)d_in[9];
  const float* b_out = (const float*)d_in[10];
  const float* gamma = (const float*)d_in[11];
  const float* beta  = (const float*)d_in[12];
  float* ws = (float*)d_ws;
  float* xp     = ws + OFF_XP;
  float* xs     = ws + OFF_XS;
  float* Bm     = ws + OFF_BM;
  float* Cm     = ws + OFF_CM;
  float* carry  = ws + OFF_CARRY;
  __bf16* xbf   = (__bf16*)xs;
  __bf16* ybf   = (__bf16*)xp;
  float* outpre = xs;
  float* out    = (float*)d_out;

  k_xpose<<<dim3(64, 4, 4), 256, 0, stream>>>(x, xbf);
  k_gemm<<<dim3(64, 8, 4), 256, 0, stream>>>(w_in, xbf, 256, b_in, xp, 512);
  k_conv<<<dim3(256, 4), 256, 0, stream>>>(xp, wconv, bconv, xs);
  k_bc<<<dim3(256, 4), 256, 0, stream>>>(xs, Bw, Cw, Bm, Cm);
  k_scan_local<<<dim3(NCH, 4), 512, 0, stream>>>(xp, Bm, A_log, carry);
  k_carry<<<64, 256, 0, stream>>>(A_log, carry);
  k_scan_y<<<dim3(NCH, 4), 512, 0, stream>>>(xp, xs, Bm, Cm, A_log, Dsk, carry, ybf);
  k_gemm<<<dim3(64, 4, 4), 256, 0, stream>>>(w_out, ybf, 1024, b_out, outpre, 256);
  k_ln<<<dim3(128, 4), 256, 0, stream>>>(outpre, x, gamma, beta, out);
}

// Round 4
// 183.310 us; speedup vs baseline: 1.5571x; 1.0466x over previous
//
#include <hip/hip_runtime.h>
#include <math.h>

#define NPTS 4096
#define NB   4
#define NCH  128   // scan chunks
#define CHL  32    // chunk length (NCH*CHL == NPTS)

// ---- workspace offsets (floats); total 17,301,504 floats = 69.2 MB (ws = 256 MiB) ----
// xs region lifecycle: xbf (k_xpose -> in_proj gemm) -> xs (k_convbc -> k_scan_y) -> outpre (out_proj gemm -> k_ln)
// xp region: in_proj out [B][N][512]; x1 half (floats 0..255 of each row) dies after k_convbc,
//            reused as bf16 y storage (ushorts 0..255 of each row) written by k_scan_y.
#define OFF_XP     0          // [B][N][512]
#define OFF_XS     8388608    // [B][N][256]
#define OFF_BM     12582912   // [B][N][16]
#define OFF_CM     12845056   // [B][N][16]
#define OFF_CARRY  13107200   // [B][NCH][256][16] local chunk end-states
#define OFF_CARRY2 15204352   // [B][NCH][256][16] exclusive-prefix carry-in states

typedef __bf16 bf16x8 __attribute__((ext_vector_type(8)));
typedef __bf16 bf16x4 __attribute__((ext_vector_type(4)));
typedef float  f32x4  __attribute__((ext_vector_type(4)));

__device__ __forceinline__ float sigmoidf_(float v) { return 1.f / (1.f + expf(-v)); }

// ===== K0: transpose+convert x [B][C][N] fp32 -> xbf [B][N][C] bf16
__global__ __launch_bounds__(256) void k_xpose(const float* __restrict__ x,
                                               __bf16* __restrict__ xbf) {
  const int b = blockIdx.z, c0 = blockIdx.y << 6, t0 = blockIdx.x << 6;
  const int tid = threadIdx.x;
  __shared__ float tile[64 * 65];
  #pragma unroll
  for (int r = 0; r < 4; ++r) {
    int cc = (r << 4) + (tid >> 4), tt4 = (tid & 15) << 2;
    float4 v = *(const float4*)&x[((size_t)(b * 256 + c0 + cc)) * NPTS + t0 + tt4];
    tile[cc * 65 + tt4 + 0] = v.x;
    tile[cc * 65 + tt4 + 1] = v.y;
    tile[cc * 65 + tt4 + 2] = v.z;
    tile[cc * 65 + tt4 + 3] = v.w;
  }
  __syncthreads();
  #pragma unroll
  for (int r = 0; r < 4; ++r) {
    int tt = (r << 4) + (tid >> 4), cc4 = (tid & 15) << 2;
    bf16x4 o;
    o[0] = (__bf16)tile[(cc4 + 0) * 65 + tt];
    o[1] = (__bf16)tile[(cc4 + 1) * 65 + tt];
    o[2] = (__bf16)tile[(cc4 + 2) * 65 + tt];
    o[3] = (__bf16)tile[(cc4 + 3) * 65 + tt];
    *(bf16x4*)&xbf[((size_t)(b * NPTS + t0 + tt)) * 256 + c0 + cc4] = o;
  }
}

// ===== bf16 MFMA GEMM: Out[b][t][o] = sum_k W[o][k]*Bop[b][t][k] + bias[o]
__global__ __launch_bounds__(256) void k_gemm(const float* __restrict__ W,
                                              const __bf16* __restrict__ Bop, int bstride,
                                              const float* __restrict__ bias,
                                              float* __restrict__ Out, int ostride) {
  const int b = blockIdx.z, o0 = blockIdx.y << 6, t0 = blockIdx.x << 6;
  const int tid = threadIdx.x, lane = tid & 63, wv = tid >> 6;
  const int mo = (wv & 1) << 5, no = (wv >> 1) << 5;
  __shared__ __align__(16) float smem[64 * 68];
  __bf16* Al = (__bf16*)smem;
  __bf16* Bl = Al + 4096;
  float* Cl = smem;

  f32x4 acc[2][2] = {};
  for (int k0 = 0; k0 < 256; k0 += 64) {
    __syncthreads();
    #pragma unroll
    for (int r = 0; r < 4; ++r) {
      int idx = (r << 8) + tid;
      int oo = idx >> 4, kk = (idx & 15) << 2;
      float4 v = *(const float4*)&W[((size_t)(o0 + oo)) * 256 + k0 + kk];
      bf16x4 p;
      p[0] = (__bf16)v.x; p[1] = (__bf16)v.y; p[2] = (__bf16)v.z; p[3] = (__bf16)v.w;
      *(bf16x4*)&Al[oo * 64 + kk] = p;
    }
    #pragma unroll
    for (int r = 0; r < 2; ++r) {
      int idx = (r << 8) + tid;
      int tt = idx >> 3, k8 = (idx & 7) << 3;
      *(uint4*)&Bl[tt * 64 + k8] =
          *(const uint4*)&Bop[((size_t)(b * NPTS + t0 + tt)) * bstride + k0 + k8];
    }
    __syncthreads();
    #pragma unroll
    for (int kc = 0; kc < 64; kc += 32) {
      int kb = kc + ((lane >> 4) << 3);
      bf16x8 a0 = *(bf16x8*)&Al[(mo + (lane & 15)) * 64 + kb];
      bf16x8 a1 = *(bf16x8*)&Al[(mo + 16 + (lane & 15)) * 64 + kb];
      bf16x8 b0 = *(bf16x8*)&Bl[(no + (lane & 15)) * 64 + kb];
      bf16x8 b1 = *(bf16x8*)&Bl[(no + 16 + (lane & 15)) * 64 + kb];
      acc[0][0] = __builtin_amdgcn_mfma_f32_16x16x32_bf16(a0, b0, acc[0][0], 0, 0, 0);
      acc[0][1] = __builtin_amdgcn_mfma_f32_16x16x32_bf16(a0, b1, acc[0][1], 0, 0, 0);
      acc[1][0] = __builtin_amdgcn_mfma_f32_16x16x32_bf16(a1, b0, acc[1][0], 0, 0, 0);
      acc[1][1] = __builtin_amdgcn_mfma_f32_16x16x32_bf16(a1, b1, acc[1][1], 0, 0, 0);
    }
  }
  __syncthreads();
  #pragma unroll
  for (int mi = 0; mi < 2; ++mi)
    #pragma unroll
    for (int ni = 0; ni < 2; ++ni) {
      int t_loc = no + (ni << 4) + (lane & 15);
      int o_b = mo + (mi << 4) + ((lane >> 4) << 2);
      #pragma unroll
      for (int rg = 0; rg < 4; ++rg)
        Cl[t_loc * 68 + o_b + rg] = acc[mi][ni][rg];
    }
  __syncthreads();
  #pragma unroll
  for (int r = 0; r < 4; ++r) {
    int tt = (r << 4) + (tid >> 4), oo4 = (tid & 15) << 2;
    float4 v = *(float4*)&Cl[tt * 68 + oo4];
    float4 bi = *(const float4*)&bias[o0 + oo4];
    v.x += bi.x; v.y += bi.y; v.z += bi.z; v.w += bi.w;
    *(float4*)&Out[((size_t)(b * NPTS + t0 + tt)) * ostride + o0 + oo4] = v;
  }
}

// ===== K2: fused depthwise causal conv (w=4)+silu -> xs & LDS, then Bm/Cm projection
// grid (N/16, B), 256 thr
__global__ __launch_bounds__(256) void k_convbc(const float* __restrict__ xp,
                                                const float* __restrict__ wconv,
                                                const float* __restrict__ bconv,
                                                const float* __restrict__ Bw,
                                                const float* __restrict__ Cw,
                                                float* __restrict__ xs,
                                                float* __restrict__ Bm,
                                                float* __restrict__ Cm) {
  const int b = blockIdx.y, t0 = blockIdx.x << 4, d = threadIdx.x;
  __shared__ __align__(16) float xt[16][256];
  __shared__ __align__(16) float Bl[16][260];
  __shared__ __align__(16) float Cl[16][260];
  #pragma unroll
  for (int r = 0; r < 4; ++r) {
    int idx = r * 256 + d;
    int s = idx >> 6, dg = (idx & 63) << 2;
    *(float4*)&Bl[s][dg] = *(const float4*)&Bw[s * 256 + dg];
    *(float4*)&Cl[s][dg] = *(const float4*)&Cw[s * 256 + dg];
  }
  const float4 wc = *(const float4*)&wconv[d << 2];
  const float bc = bconv[d];
  float xm3 = 0.f, xm2 = 0.f, xm1 = 0.f;
  if (t0 > 0) {
    int bb = (b * NPTS + t0) * 512 + d;
    xm3 = xp[bb - 3 * 512];
    xm2 = xp[bb - 2 * 512];
    xm1 = xp[bb - 1 * 512];
  }
  #pragma unroll
  for (int i = 0; i < 16; ++i) {
    int t = t0 + i;
    float xc = xp[(b * NPTS + t) * 512 + d];
    float cv = fmaf(wc.x, xm3, fmaf(wc.y, xm2, fmaf(wc.z, xm1, fmaf(wc.w, xc, bc))));
    float sv = cv * sigmoidf_(cv);
    xt[i][d] = sv;
    xs[(b * NPTS + t) * 256 + d] = sv;
    xm3 = xm2; xm2 = xm1; xm1 = xc;
  }
  __syncthreads();
  const int s = d & 15, tl = d >> 4;
  float accB = 0.f, accC = 0.f;
  #pragma unroll 8
  for (int dd = 0; dd < 256; dd += 4) {
    float4 xv = *(float4*)&xt[tl][dd];
    float4 bv = *(float4*)&Bl[s][dd];
    float4 cv = *(float4*)&Cl[s][dd];
    accB += xv.x * bv.x + xv.y * bv.y + xv.z * bv.z + xv.w * bv.w;
    accC += xv.x * cv.x + xv.y * cv.y + xv.z * cv.z + xv.w * cv.w;
  }
  int row = (b * NPTS + t0 + tl) * 16 + s;
  Bm[row] = accB;
  Cm[row] = accC;
}

// ===== K4a: per-chunk local scan (h=0 start), store end state
__global__ __launch_bounds__(512) void k_scan_local(const float* __restrict__ xp,
                                                    const float* __restrict__ Bm,
                                                    const float* __restrict__ A_log,
                                                    float* __restrict__ carry) {
  const int b = blockIdx.y, ch = blockIdx.x;
  const int tid = threadIdx.x;
  const int d = tid >> 1, sh = (tid & 1) << 3;
  __shared__ __align__(16) float bm[CHL][16];
  {
    int t = tid >> 4, s = tid & 15;
    bm[t][s] = Bm[(b * NPTS + (ch << 5) + t) * 16 + s];
  }
  float a[8], h[8];
  {
    float4 a0 = *(const float4*)&A_log[(d << 4) + sh];
    float4 a1 = *(const float4*)&A_log[(d << 4) + sh + 4];
    a[0] = -expf(a0.x); a[1] = -expf(a0.y); a[2] = -expf(a0.z); a[3] = -expf(a0.w);
    a[4] = -expf(a1.x); a[5] = -expf(a1.y); a[6] = -expf(a1.z); a[7] = -expf(a1.w);
  }
  #pragma unroll
  for (int s = 0; s < 8; ++s) h[s] = 0.f;
  __syncthreads();
  const size_t zbase = ((size_t)(b * NPTS + (ch << 5))) * 512 + 256 + d;
  float zn[4];
  #pragma unroll
  for (int k = 0; k < 4; ++k) zn[k] = xp[zbase + ((size_t)k << 9)];
  for (int g = 0; g < CHL / 4; ++g) {
    float zc[4];
    #pragma unroll
    for (int k = 0; k < 4; ++k) zc[k] = zn[k];
    if (g < CHL / 4 - 1) {
      #pragma unroll
      for (int k = 0; k < 4; ++k) zn[k] = xp[zbase + ((size_t)((g + 1) * 4 + k) << 9)];
    }
    #pragma unroll
    for (int k = 0; k < 4; ++k) {
      int i = g * 4 + k;
      float u = sigmoidf_(zc[k]);
      float4 b0 = *(float4*)&bm[i][sh];
      float4 b1 = *(float4*)&bm[i][sh + 4];
      h[0] = fmaf(a[0], h[0], u * b0.x);
      h[1] = fmaf(a[1], h[1], u * b0.y);
      h[2] = fmaf(a[2], h[2], u * b0.z);
      h[3] = fmaf(a[3], h[3], u * b0.w);
      h[4] = fmaf(a[4], h[4], u * b1.x);
      h[5] = fmaf(a[5], h[5], u * b1.y);
      h[6] = fmaf(a[6], h[6], u * b1.z);
      h[7] = fmaf(a[7], h[7], u * b1.w);
    }
  }
  int cb = (((b * NCH + ch) << 8) + d) * 16 + sh;
  *(float4*)&carry[cb]     = make_float4(h[0], h[1], h[2], h[3]);
  *(float4*)&carry[cb + 4] = make_float4(h[4], h[5], h[6], h[7]);
}

// ===== K4b: exclusive-prefix carry combine, src->dst (no aliasing => pipelined loads)
// 16384 threads, one per (b,d,s); groups of 16 chunks with next-group prefetch
__global__ __launch_bounds__(256) void k_carry(const float* __restrict__ src,
                                               const float* __restrict__ A_log,
                                               float* __restrict__ dst) {
  int g = blockIdx.x * 256 + threadIdx.x;
  int s = g & 15, d = (g >> 4) & 255, b = g >> 12;
  float a = -expf(A_log[(d << 4) + s]);
  float aL = a;
  #pragma unroll
  for (int i = 0; i < 5; ++i) aL *= aL;  // a^CHL (CHL=32)
  const int base = ((b * NCH) << 12) + (d << 4) + s;  // + ch*4096
  float hs = 0.f;
  float cur[16], nxt[16];
  #pragma unroll
  for (int k = 0; k < 16; ++k) cur[k] = src[base + (k << 12)];
  for (int grp = 0; grp < NCH / 16; ++grp) {
    if (grp < NCH / 16 - 1) {
      #pragma unroll
      for (int k = 0; k < 16; ++k)
        nxt[k] = src[base + (((grp + 1) * 16 + k) << 12)];
    }
    #pragma unroll
    for (int k = 0; k < 16; ++k) {
      dst[base + (((grp << 4) + k) << 12)] = hs;
      hs = fmaf(aL, hs, cur[k]);
    }
    if (grp < NCH / 16 - 1) {
      #pragma unroll
      for (int k = 0; k < 16; ++k) cur[k] = nxt[k];
    }
  }
}

// ===== K4c: re-run chunks with true carry-in, emit y bf16 into dead x1 half of xp rows
__global__ __launch_bounds__(512) void k_scan_y(const float* __restrict__ xp,
                                                const float* __restrict__ xs,
                                                const float* __restrict__ Bm,
                                                const float* __restrict__ Cm,
                                                const float* __restrict__ A_log,
                                                const float* __restrict__ Dskip,
                                                const float* __restrict__ carry2,
                                                __bf16* __restrict__ ybf) {
  const int b = blockIdx.y, ch = blockIdx.x;
  const int tid = threadIdx.x;
  const int d = tid >> 1, sh = (tid & 1) << 3;
  __shared__ __align__(16) float bm[CHL][16];
  __shared__ __align__(16) float cm[CHL][16];
  {
    int rowbase = (b * NPTS + (ch << 5)) * 16;
    bm[0][tid] = Bm[rowbase + tid];
    cm[0][tid] = Cm[rowbase + tid];
  }
  float a[8], h[8];
  {
    float4 a0 = *(const float4*)&A_log[(d << 4) + sh];
    float4 a1 = *(const float4*)&A_log[(d << 4) + sh + 4];
    a[0] = -expf(a0.x); a[1] = -expf(a0.y); a[2] = -expf(a0.z); a[3] = -expf(a0.w);
    a[4] = -expf(a1.x); a[5] = -expf(a1.y); a[6] = -expf(a1.z); a[7] = -expf(a1.w);
  }
  {
    int cb = (((b * NCH + ch) << 8) + d) * 16 + sh;
    float4 h0 = *(const float4*)&carry2[cb];
    float4 h1 = *(const float4*)&carry2[cb + 4];
    h[0] = h0.x; h[1] = h0.y; h[2] = h0.z; h[3] = h0.w;
    h[4] = h1.x; h[5] = h1.y; h[6] = h1.z; h[7] = h1.w;
  }
  const float Dv = Dskip[d];
  __syncthreads();
  const size_t base  = ((size_t)(b * NPTS + (ch << 5))) * 256 + d;
  const size_t zbase = ((size_t)(b * NPTS + (ch << 5))) * 512 + 256 + d;
  const size_t ybase = ((size_t)(b * NPTS + (ch << 5))) * 1024 + d;
  float zn[4], xn[4];
  #pragma unroll
  for (int k = 0; k < 4; ++k) {
    zn[k] = xp[zbase + ((size_t)k << 9)];
    xn[k] = xs[base + ((size_t)k << 8)];
  }
  for (int g = 0; g < CHL / 4; ++g) {
    float zc[4], xc[4];
    #pragma unroll
    for (int k = 0; k < 4; ++k) { zc[k] = zn[k]; xc[k] = xn[k]; }
    if (g < CHL / 4 - 1) {
      #pragma unroll
      for (int k = 0; k < 4; ++k) {
        zn[k] = xp[zbase + ((size_t)((g + 1) * 4 + k) << 9)];
        xn[k] = xs[base + ((size_t)((g + 1) * 4 + k) << 8)];
      }
    }
    #pragma unroll
    for (int k = 0; k < 4; ++k) {
      int i = g * 4 + k;
      float u = sigmoidf_(zc[k]);
      float4 b0 = *(float4*)&bm[i][sh];
      float4 b1 = *(float4*)&bm[i][sh + 4];
      float4 c0 = *(float4*)&cm[i][sh];
      float4 c1 = *(float4*)&cm[i][sh + 4];
      h[0] = fmaf(a[0], h[0], u * b0.x);
      h[1] = fmaf(a[1], h[1], u * b0.y);
      h[2] = fmaf(a[2], h[2], u * b0.z);
      h[3] = fmaf(a[3], h[3], u * b0.w);
      h[4] = fmaf(a[4], h[4], u * b1.x);
      h[5] = fmaf(a[5], h[5], u * b1.y);
      h[6] = fmaf(a[6], h[6], u * b1.z);
      h[7] = fmaf(a[7], h[7], u * b1.w);
      float yv = h[0] * c0.x + h[1] * c0.y + h[2] * c0.z + h[3] * c0.w
               + h[4] * c1.x + h[5] * c1.y + h[6] * c1.z + h[7] * c1.w;
      yv += __shfl_xor(yv, 1);
      if ((tid & 1) == 0)
        ybf[ybase + ((size_t)i << 10)] = (__bf16)fmaf(Dv, xc[k], yv);
    }
  }
}

// ===== K6: residual add + LayerNorm over C + transpose to [B][C][N]
__global__ __launch_bounds__(256) void k_ln(const float* __restrict__ outpre,
                                            const float* __restrict__ x,
                                            const float* __restrict__ gamma,
                                            const float* __restrict__ beta,
                                            float* __restrict__ out) {
  const int b = blockIdx.y, t0 = blockIdx.x << 5;
  const int tid = threadIdx.x, lane = tid & 63, w = tid >> 6;
  __shared__ float xres[256][33];
  #pragma unroll
  for (int r = 0; r < 8; ++r) {
    int lin = (r * 256 + tid) << 2;
    int c = lin >> 5, tg = lin & 31;
    float4 xv = *(const float4*)&x[(b * 256 + c) * NPTS + t0 + tg];
    xres[c][tg + 0] = xv.x;
    xres[c][tg + 1] = xv.y;
    xres[c][tg + 2] = xv.z;
    xres[c][tg + 3] = xv.w;
  }
  float g[4], be[4];
  #pragma unroll
  for (int j = 0; j < 4; ++j) {
    g[j] = gamma[lane + 64 * j];
    be[j] = beta[lane + 64 * j];
  }
  __syncthreads();
  for (int rr = 0; rr < 8; ++rr) {
    int trow = w * 8 + rr;
    int rowbase = (b * NPTS + t0 + trow) * 256;
    float v[4];
    float sum = 0.f, sq = 0.f;
    #pragma unroll
    for (int j = 0; j < 4; ++j) {
      int c = lane + 64 * j;
      v[j] = outpre[rowbase + c] + xres[c][trow];
      sum += v[j];
      sq += v[j] * v[j];
    }
    #pragma unroll
    for (int m = 1; m < 64; m <<= 1) {
      sum += __shfl_xor(sum, m);
      sq += __shfl_xor(sq, m);
    }
    float mean = sum * (1.f / 256.f);
    float var = sq * (1.f / 256.f) - mean * mean;
    float rstd = rsqrtf(var + 1e-5f);
    #pragma unroll
    for (int j = 0; j < 4; ++j) {
      int c = lane + 64 * j;
      xres[c][trow] = (v[j] - mean) * rstd * g[j] + be[j];
    }
  }
  __syncthreads();
  #pragma unroll
  for (int p = 0; p < 32; ++p) {
    int c = (p << 3) + (tid >> 5);
    int t = tid & 31;
    out[(b * 256 + c) * NPTS + t0 + t] = xres[c][t];
  }
}

extern "C" void kernel_launch(void* const* d_in, const int* in_sizes, int n_in,
                              void* d_out, int out_size, void* d_ws, size_t ws_size,
                              hipStream_t stream) {
  const float* x     = (const float*)d_in[0];
  const float* w_in  = (const float*)d_in[1];
  const float* b_in  = (const float*)d_in[2];
  const float* wconv = (const float*)d_in[3];
  const float* bconv = (const float*)d_in[4];
  const float* A_log = (const float*)d_in[5];
  const float* Dsk   = (const float*)d_in[6];
  const float* Bw    = (const float*)d_in[7];
  const float* Cw    = (const float*)d_in[8];
  const float* w_out = (const float*)d_in[9];
  const float* b_out = (const float*)d_in[10];
  const float* gamma = (const float*)d_in[11];
  const float* beta  = (const float*)d_in[12];
  float* ws = (float*)d_ws;
  float* xp     = ws + OFF_XP;
  float* xs     = ws + OFF_XS;
  float* Bm     = ws + OFF_BM;
  float* Cm     = ws + OFF_CM;
  float* carry  = ws + OFF_CARRY;
  float* carry2 = ws + OFF_CARRY2;
  __bf16* xbf   = (__bf16*)xs;
  __bf16* ybf   = (__bf16*)xp;
  float* outpre = xs;
  float* out    = (float*)d_out;

  k_xpose<<<dim3(64, 4, 4), 256, 0, stream>>>(x, xbf);
  k_gemm<<<dim3(64, 8, 4), 256, 0, stream>>>(w_in, xbf, 256, b_in, xp, 512);
  k_convbc<<<dim3(256, 4), 256, 0, stream>>>(xp, wconv, bconv, Bw, Cw, xs, Bm, Cm);
  k_scan_local<<<dim3(NCH, 4), 512, 0, stream>>>(xp, Bm, A_log, carry);
  k_carry<<<64, 256, 0, stream>>>(carry, A_log, carry2);
  k_scan_y<<<dim3(NCH, 4), 512, 0, stream>>>(xp, xs, Bm, Cm, A_log, Dsk, carry2, ybf);
  k_gemm<<<dim3(64, 4, 4), 256, 0, stream>>>(w_out, ybf, 1024, b_out, outpre, 256);
  k_ln<<<dim3(128, 4), 256, 0, stream>>>(outpre, x, gamma, beta, out);
}

// Round 5
// 172.879 us; speedup vs baseline: 1.6510x; 1.0603x over previous
//
#include <hip/hip_runtime.h>
#include <math.h>

#define NPTS 4096
#define NB   4
#define NCH  128   // scan chunks
#define CHL  32    // chunk length (NCH*CHL == NPTS)

// ---- workspace offsets (float units); total 15,204,352 floats = 60.8 MB ----
#define OFF_XBF    0          // bf16 [B][N][256] x transposed
#define OFF_X1B    2097152    // bf16 [B][N][256] in_proj x1 half (bias applied)
#define OFF_DELTA  4194304    // bf16 [B][N][256] sigmoid(z+bias)
#define OFF_XSB    6291456    // bf16 [B][N][256] silu(conv)
#define OFF_YBF    8388608    // bf16 [B][N][256] scan output y
#define OFF_BM     10485760   // f32 [B][N][16]
#define OFF_CM     10747904   // f32 [B][N][16]
#define OFF_CARRY  11010048   // f32 [B][NCH][256][16] local chunk end-states
#define OFF_CARRY2 13107200   // f32 [B][NCH][256][16] exclusive-prefix carries

typedef __bf16 bf16x8 __attribute__((ext_vector_type(8)));
typedef __bf16 bf16x4 __attribute__((ext_vector_type(4)));
typedef float  f32x4  __attribute__((ext_vector_type(4)));

__device__ __forceinline__ float sigmoidf_(float v) { return 1.f / (1.f + expf(-v)); }

// ===== K0: transpose+convert x [B][C][N] fp32 -> xbf [B][N][C] bf16
__global__ __launch_bounds__(256) void k_xpose(const float* __restrict__ x,
                                               __bf16* __restrict__ xbf) {
  const int b = blockIdx.z, c0 = blockIdx.y << 6, t0 = blockIdx.x << 6;
  const int tid = threadIdx.x;
  __shared__ float tile[64 * 65];
  #pragma unroll
  for (int r = 0; r < 4; ++r) {
    int cc = (r << 4) + (tid >> 4), tt4 = (tid & 15) << 2;
    float4 v = *(const float4*)&x[((size_t)(b * 256 + c0 + cc)) * NPTS + t0 + tt4];
    tile[cc * 65 + tt4 + 0] = v.x;
    tile[cc * 65 + tt4 + 1] = v.y;
    tile[cc * 65 + tt4 + 2] = v.z;
    tile[cc * 65 + tt4 + 3] = v.w;
  }
  __syncthreads();
  #pragma unroll
  for (int r = 0; r < 4; ++r) {
    int tt = (r << 4) + (tid >> 4), cc4 = (tid & 15) << 2;
    bf16x4 o;
    o[0] = (__bf16)tile[(cc4 + 0) * 65 + tt];
    o[1] = (__bf16)tile[(cc4 + 1) * 65 + tt];
    o[2] = (__bf16)tile[(cc4 + 2) * 65 + tt];
    o[3] = (__bf16)tile[(cc4 + 3) * 65 + tt];
    *(bf16x4*)&xbf[((size_t)(b * NPTS + t0 + tt)) * 256 + c0 + cc4] = o;
  }
}

// ===== K1: in_proj MFMA GEMM with fused activation epilogue
// xp[o] = sum_k w_in[o][k]*xbf[t][k] + b_in[o]; o<256 -> x1b bf16; o>=256 -> delta=sigmoid bf16
// LDS tiles XOR-swizzled in 16B chunks to kill 16-way frag-read conflicts.
__global__ __launch_bounds__(256) void k_inproj(const float* __restrict__ W,
                                                const __bf16* __restrict__ Bop,
                                                const float* __restrict__ bias,
                                                __bf16* __restrict__ x1b,
                                                __bf16* __restrict__ delta) {
  const int b = blockIdx.z, o0 = blockIdx.y << 6, t0 = blockIdx.x << 6;
  const int tid = threadIdx.x, lane = tid & 63, wv = tid >> 6;
  const int mo = (wv & 1) << 5, no = (wv >> 1) << 5;
  __shared__ __align__(16) float smem[64 * 68];
  __bf16* Al = (__bf16*)smem;   // [64][64] row=o, swizzled chunks
  __bf16* Bl = Al + 4096;       // [64][64] row=t, swizzled chunks
  float* Cl = smem;             // epilogue fp32 [64][68]

  f32x4 acc[2][2] = {};
  for (int k0 = 0; k0 < 256; k0 += 64) {
    __syncthreads();
    #pragma unroll
    for (int r = 0; r < 4; ++r) {
      int idx = (r << 8) + tid;
      int oo = idx >> 4, kk = (idx & 15) << 2;
      float4 v = *(const float4*)&W[((size_t)(o0 + oo)) * 256 + k0 + kk];
      bf16x4 p;
      p[0] = (__bf16)v.x; p[1] = (__bf16)v.y; p[2] = (__bf16)v.z; p[3] = (__bf16)v.w;
      *(bf16x4*)&Al[oo * 64 + ((((kk >> 3) ^ (oo & 7))) << 3) + (kk & 7)] = p;
    }
    #pragma unroll
    for (int r = 0; r < 2; ++r) {
      int idx = (r << 8) + tid;
      int tt = idx >> 3, ch = idx & 7;
      *(uint4*)&Bl[tt * 64 + ((ch ^ (tt & 7)) << 3)] =
          *(const uint4*)&Bop[((size_t)(b * NPTS + t0 + tt)) * 256 + k0 + (ch << 3)];
    }
    __syncthreads();
    #pragma unroll
    for (int kc = 0; kc < 64; kc += 32) {
      int ch0 = (kc >> 3) + (lane >> 4);   // chunk index 0..7
      int ra0 = mo + (lane & 15), ra1 = ra0 + 16;
      int rb0 = no + (lane & 15), rb1 = rb0 + 16;
      bf16x8 a0 = *(bf16x8*)&Al[ra0 * 64 + ((ch0 ^ (ra0 & 7)) << 3)];
      bf16x8 a1 = *(bf16x8*)&Al[ra1 * 64 + ((ch0 ^ (ra1 & 7)) << 3)];
      bf16x8 b0 = *(bf16x8*)&Bl[rb0 * 64 + ((ch0 ^ (rb0 & 7)) << 3)];
      bf16x8 b1 = *(bf16x8*)&Bl[rb1 * 64 + ((ch0 ^ (rb1 & 7)) << 3)];
      acc[0][0] = __builtin_amdgcn_mfma_f32_16x16x32_bf16(a0, b0, acc[0][0], 0, 0, 0);
      acc[0][1] = __builtin_amdgcn_mfma_f32_16x16x32_bf16(a0, b1, acc[0][1], 0, 0, 0);
      acc[1][0] = __builtin_amdgcn_mfma_f32_16x16x32_bf16(a1, b0, acc[1][0], 0, 0, 0);
      acc[1][1] = __builtin_amdgcn_mfma_f32_16x16x32_bf16(a1, b1, acc[1][1], 0, 0, 0);
    }
  }
  __syncthreads();
  #pragma unroll
  for (int mi = 0; mi < 2; ++mi)
    #pragma unroll
    for (int ni = 0; ni < 2; ++ni) {
      int t_loc = no + (ni << 4) + (lane & 15);
      int o_b = mo + (mi << 4) + ((lane >> 4) << 2);
      #pragma unroll
      for (int rg = 0; rg < 4; ++rg)
        Cl[t_loc * 68 + o_b + rg] = acc[mi][ni][rg];
    }
  __syncthreads();
  #pragma unroll
  for (int r = 0; r < 4; ++r) {
    int tt = (r << 4) + (tid >> 4), oo4 = (tid & 15) << 2;
    float4 v = *(float4*)&Cl[tt * 68 + oo4];
    float4 bi = *(const float4*)&bias[o0 + oo4];
    v.x += bi.x; v.y += bi.y; v.z += bi.z; v.w += bi.w;
    bf16x4 p;
    if (o0 < 256) {                      // x1 half
      p[0] = (__bf16)v.x; p[1] = (__bf16)v.y; p[2] = (__bf16)v.z; p[3] = (__bf16)v.w;
      *(bf16x4*)&x1b[((size_t)(b * NPTS + t0 + tt)) * 256 + o0 + oo4] = p;
    } else {                             // z half -> sigmoid -> delta
      p[0] = (__bf16)sigmoidf_(v.x); p[1] = (__bf16)sigmoidf_(v.y);
      p[2] = (__bf16)sigmoidf_(v.z); p[3] = (__bf16)sigmoidf_(v.w);
      *(bf16x4*)&delta[((size_t)(b * NPTS + t0 + tt)) * 256 + (o0 - 256) + oo4] = p;
    }
  }
}

// ===== K2: fused depthwise causal conv (w=4)+silu -> xsb bf16 & LDS, then Bm/Cm projection
__global__ __launch_bounds__(256) void k_convbc(const __bf16* __restrict__ x1b,
                                                const float* __restrict__ wconv,
                                                const float* __restrict__ bconv,
                                                const float* __restrict__ Bw,
                                                const float* __restrict__ Cw,
                                                __bf16* __restrict__ xsb,
                                                float* __restrict__ Bm,
                                                float* __restrict__ Cm) {
  const int b = blockIdx.y, t0 = blockIdx.x << 4, d = threadIdx.x;
  __shared__ __align__(16) float xt[16][256];
  __shared__ __align__(16) float Bl[16][260];
  __shared__ __align__(16) float Cl[16][260];
  #pragma unroll
  for (int r = 0; r < 4; ++r) {
    int idx = r * 256 + d;
    int s = idx >> 6, dg = (idx & 63) << 2;
    *(float4*)&Bl[s][dg] = *(const float4*)&Bw[s * 256 + dg];
    *(float4*)&Cl[s][dg] = *(const float4*)&Cw[s * 256 + dg];
  }
  const float4 wc = *(const float4*)&wconv[d << 2];
  const float bc = bconv[d];
  float xm3 = 0.f, xm2 = 0.f, xm1 = 0.f;
  if (t0 > 0) {
    size_t bb = ((size_t)(b * NPTS + t0)) * 256 + d;
    xm3 = (float)x1b[bb - 3 * 256];
    xm2 = (float)x1b[bb - 2 * 256];
    xm1 = (float)x1b[bb - 1 * 256];
  }
  #pragma unroll
  for (int i = 0; i < 16; ++i) {
    size_t idx = ((size_t)(b * NPTS + t0 + i)) * 256 + d;
    float xc = (float)x1b[idx];
    float cv = fmaf(wc.x, xm3, fmaf(wc.y, xm2, fmaf(wc.z, xm1, fmaf(wc.w, xc, bc))));
    float sv = cv * sigmoidf_(cv);
    xt[i][d] = sv;
    xsb[idx] = (__bf16)sv;
    xm3 = xm2; xm2 = xm1; xm1 = xc;
  }
  __syncthreads();
  const int s = d & 15, tl = d >> 4;
  float accB = 0.f, accC = 0.f;
  #pragma unroll 8
  for (int dd = 0; dd < 256; dd += 4) {
    float4 xv = *(float4*)&xt[tl][dd];
    float4 bv = *(float4*)&Bl[s][dd];
    float4 cv = *(float4*)&Cl[s][dd];
    accB += xv.x * bv.x + xv.y * bv.y + xv.z * bv.z + xv.w * bv.w;
    accC += xv.x * cv.x + xv.y * cv.y + xv.z * cv.z + xv.w * cv.w;
  }
  int row = (b * NPTS + t0 + tl) * 16 + s;
  Bm[row] = accB;
  Cm[row] = accC;
}

// ===== K4a: per-chunk local scan (h=0 start), store end state
__global__ __launch_bounds__(512) void k_scan_local(const __bf16* __restrict__ delta,
                                                    const float* __restrict__ Bm,
                                                    const float* __restrict__ A_log,
                                                    float* __restrict__ carry) {
  const int b = blockIdx.y, ch = blockIdx.x;
  const int tid = threadIdx.x;
  const int d = tid >> 1, sh = (tid & 1) << 3;
  __shared__ __align__(16) float bm[CHL][16];
  {
    int t = tid >> 4, s = tid & 15;
    bm[t][s] = Bm[(b * NPTS + (ch << 5) + t) * 16 + s];
  }
  float a[8], h[8];
  {
    float4 a0 = *(const float4*)&A_log[(d << 4) + sh];
    float4 a1 = *(const float4*)&A_log[(d << 4) + sh + 4];
    a[0] = -expf(a0.x); a[1] = -expf(a0.y); a[2] = -expf(a0.z); a[3] = -expf(a0.w);
    a[4] = -expf(a1.x); a[5] = -expf(a1.y); a[6] = -expf(a1.z); a[7] = -expf(a1.w);
  }
  #pragma unroll
  for (int s = 0; s < 8; ++s) h[s] = 0.f;
  __syncthreads();
  const size_t zbase = ((size_t)(b * NPTS + (ch << 5))) * 256 + d;
  float zn[4];
  #pragma unroll
  for (int k = 0; k < 4; ++k) zn[k] = (float)delta[zbase + ((size_t)k << 8)];
  for (int g = 0; g < CHL / 4; ++g) {
    float zc[4];
    #pragma unroll
    for (int k = 0; k < 4; ++k) zc[k] = zn[k];
    if (g < CHL / 4 - 1) {
      #pragma unroll
      for (int k = 0; k < 4; ++k)
        zn[k] = (float)delta[zbase + ((size_t)((g + 1) * 4 + k) << 8)];
    }
    #pragma unroll
    for (int k = 0; k < 4; ++k) {
      int i = g * 4 + k;
      float u = zc[k];   // sigmoid pre-applied
      float4 b0 = *(float4*)&bm[i][sh];
      float4 b1 = *(float4*)&bm[i][sh + 4];
      h[0] = fmaf(a[0], h[0], u * b0.x);
      h[1] = fmaf(a[1], h[1], u * b0.y);
      h[2] = fmaf(a[2], h[2], u * b0.z);
      h[3] = fmaf(a[3], h[3], u * b0.w);
      h[4] = fmaf(a[4], h[4], u * b1.x);
      h[5] = fmaf(a[5], h[5], u * b1.y);
      h[6] = fmaf(a[6], h[6], u * b1.z);
      h[7] = fmaf(a[7], h[7], u * b1.w);
    }
  }
  int cb = (((b * NCH + ch) << 8) + d) * 16 + sh;
  *(float4*)&carry[cb]     = make_float4(h[0], h[1], h[2], h[3]);
  *(float4*)&carry[cb + 4] = make_float4(h[4], h[5], h[6], h[7]);
}

// ===== K4b: exclusive-prefix carry combine, src->dst (pipelined loads)
__global__ __launch_bounds__(256) void k_carry(const float* __restrict__ src,
                                               const float* __restrict__ A_log,
                                               float* __restrict__ dst) {
  int g = blockIdx.x * 256 + threadIdx.x;
  int s = g & 15, d = (g >> 4) & 255, b = g >> 12;
  float a = -expf(A_log[(d << 4) + s]);
  float aL = a;
  #pragma unroll
  for (int i = 0; i < 5; ++i) aL *= aL;  // a^CHL (CHL=32)
  const int base = ((b * NCH) << 12) + (d << 4) + s;
  float hs = 0.f;
  float cur[16], nxt[16];
  #pragma unroll
  for (int k = 0; k < 16; ++k) cur[k] = src[base + (k << 12)];
  for (int grp = 0; grp < NCH / 16; ++grp) {
    if (grp < NCH / 16 - 1) {
      #pragma unroll
      for (int k = 0; k < 16; ++k)
        nxt[k] = src[base + (((grp + 1) * 16 + k) << 12)];
    }
    #pragma unroll
    for (int k = 0; k < 16; ++k) {
      dst[base + (((grp << 4) + k) << 12)] = hs;
      hs = fmaf(aL, hs, cur[k]);
    }
    if (grp < NCH / 16 - 1) {
      #pragma unroll
      for (int k = 0; k < 16; ++k) cur[k] = nxt[k];
    }
  }
}

// ===== K4c: re-run chunks with true carry-in, emit y bf16
__global__ __launch_bounds__(512) void k_scan_y(const __bf16* __restrict__ delta,
                                                const __bf16* __restrict__ xsb,
                                                const float* __restrict__ Bm,
                                                const float* __restrict__ Cm,
                                                const float* __restrict__ A_log,
                                                const float* __restrict__ Dskip,
                                                const float* __restrict__ carry2,
                                                __bf16* __restrict__ ybf) {
  const int b = blockIdx.y, ch = blockIdx.x;
  const int tid = threadIdx.x;
  const int d = tid >> 1, sh = (tid & 1) << 3;
  __shared__ __align__(16) float bm[CHL][16];
  __shared__ __align__(16) float cm[CHL][16];
  {
    int rowbase = (b * NPTS + (ch << 5)) * 16;
    bm[0][tid] = Bm[rowbase + tid];
    cm[0][tid] = Cm[rowbase + tid];
  }
  float a[8], h[8];
  {
    float4 a0 = *(const float4*)&A_log[(d << 4) + sh];
    float4 a1 = *(const float4*)&A_log[(d << 4) + sh + 4];
    a[0] = -expf(a0.x); a[1] = -expf(a0.y); a[2] = -expf(a0.z); a[3] = -expf(a0.w);
    a[4] = -expf(a1.x); a[5] = -expf(a1.y); a[6] = -expf(a1.z); a[7] = -expf(a1.w);
  }
  {
    int cb = (((b * NCH + ch) << 8) + d) * 16 + sh;
    float4 h0 = *(const float4*)&carry2[cb];
    float4 h1 = *(const float4*)&carry2[cb + 4];
    h[0] = h0.x; h[1] = h0.y; h[2] = h0.z; h[3] = h0.w;
    h[4] = h1.x; h[5] = h1.y; h[6] = h1.z; h[7] = h1.w;
  }
  const float Dv = Dskip[d];
  __syncthreads();
  const size_t base = ((size_t)(b * NPTS + (ch << 5))) * 256 + d;
  float zn[4], xn[4];
  #pragma unroll
  for (int k = 0; k < 4; ++k) {
    zn[k] = (float)delta[base + ((size_t)k << 8)];
    xn[k] = (float)xsb[base + ((size_t)k << 8)];
  }
  for (int g = 0; g < CHL / 4; ++g) {
    float zc[4], xc[4];
    #pragma unroll
    for (int k = 0; k < 4; ++k) { zc[k] = zn[k]; xc[k] = xn[k]; }
    if (g < CHL / 4 - 1) {
      #pragma unroll
      for (int k = 0; k < 4; ++k) {
        zn[k] = (float)delta[base + ((size_t)((g + 1) * 4 + k) << 8)];
        xn[k] = (float)xsb[base + ((size_t)((g + 1) * 4 + k) << 8)];
      }
    }
    #pragma unroll
    for (int k = 0; k < 4; ++k) {
      int i = g * 4 + k;
      float u = zc[k];
      float4 b0 = *(float4*)&bm[i][sh];
      float4 b1 = *(float4*)&bm[i][sh + 4];
      float4 c0 = *(float4*)&cm[i][sh];
      float4 c1 = *(float4*)&cm[i][sh + 4];
      h[0] = fmaf(a[0], h[0], u * b0.x);
      h[1] = fmaf(a[1], h[1], u * b0.y);
      h[2] = fmaf(a[2], h[2], u * b0.z);
      h[3] = fmaf(a[3], h[3], u * b0.w);
      h[4] = fmaf(a[4], h[4], u * b1.x);
      h[5] = fmaf(a[5], h[5], u * b1.y);
      h[6] = fmaf(a[6], h[6], u * b1.z);
      h[7] = fmaf(a[7], h[7], u * b1.w);
      float yv = h[0] * c0.x + h[1] * c0.y + h[2] * c0.z + h[3] * c0.w
               + h[4] * c1.x + h[5] * c1.y + h[6] * c1.z + h[7] * c1.w;
      yv += __shfl_xor(yv, 1);
      if ((tid & 1) == 0)
        ybf[base + ((size_t)i << 8)] = (__bf16)fmaf(Dv, xc[k], yv);
    }
  }
}

// ===== K5: fused out_proj GEMM + bias + residual + LayerNorm + transpose
// grid (N/64, B), 512 thr = 8 waves; each block: full 256-o x 64-t tile
__global__ __launch_bounds__(512) void k_outln(const float* __restrict__ W,
                                               const __bf16* __restrict__ ybf,
                                               const float* __restrict__ bias,
                                               const float* __restrict__ x,
                                               const float* __restrict__ gamma,
                                               const float* __restrict__ beta,
                                               float* __restrict__ out) {
  const int b = blockIdx.y, t0 = blockIdx.x << 6;
  const int tid = threadIdx.x, lane = tid & 63, w = tid >> 6;
  __shared__ __align__(16) float smem[64 * 257];   // 65.8 KB: staging then Ct[t][c]
  __bf16* Al = (__bf16*)smem;          // [256][64] bf16 swizzled
  __bf16* Bl = Al + 16384;             // [64][64] bf16 swizzled

  f32x4 acc[2][4] = {};
  for (int k0 = 0; k0 < 256; k0 += 64) {
    __syncthreads();
    #pragma unroll
    for (int r = 0; r < 8; ++r) {
      int idx = (r << 9) + tid;        // 0..4095
      int oo = idx >> 4, kk = (idx & 15) << 2;
      float4 v = *(const float4*)&W[(size_t)oo * 256 + k0 + kk];
      bf16x4 p;
      p[0] = (__bf16)v.x; p[1] = (__bf16)v.y; p[2] = (__bf16)v.z; p[3] = (__bf16)v.w;
      *(bf16x4*)&Al[oo * 64 + (((kk >> 3) ^ (oo & 7)) << 3) + (kk & 7)] = p;
    }
    {
      int tt = tid >> 3, ch = tid & 7;
      *(uint4*)&Bl[tt * 64 + ((ch ^ (tt & 7)) << 3)] =
          *(const uint4*)&ybf[((size_t)(b * NPTS + t0 + tt)) * 256 + k0 + (ch << 3)];
    }
    __syncthreads();
    #pragma unroll
    for (int kc = 0; kc < 64; kc += 32) {
      int ch0 = (kc >> 3) + (lane >> 4);
      int ra0 = (w << 5) + (lane & 15), ra1 = ra0 + 16;
      bf16x8 a0 = *(bf16x8*)&Al[ra0 * 64 + ((ch0 ^ (ra0 & 7)) << 3)];
      bf16x8 a1 = *(bf16x8*)&Al[ra1 * 64 + ((ch0 ^ (ra1 & 7)) << 3)];
      #pragma unroll
      for (int nt = 0; nt < 4; ++nt) {
        int rb = (nt << 4) + (lane & 15);
        bf16x8 bv = *(bf16x8*)&Bl[rb * 64 + ((ch0 ^ (rb & 7)) << 3)];
        acc[0][nt] = __builtin_amdgcn_mfma_f32_16x16x32_bf16(a0, bv, acc[0][nt], 0, 0, 0);
        acc[1][nt] = __builtin_amdgcn_mfma_f32_16x16x32_bf16(a1, bv, acc[1][nt], 0, 0, 0);
      }
    }
  }
  __syncthreads();
  // scatter frags to Ct[t][c] (stride 257)
  #pragma unroll
  for (int mi = 0; mi < 2; ++mi)
    #pragma unroll
    for (int nt = 0; nt < 4; ++nt) {
      int t = (nt << 4) + (lane & 15);
      int o = (w << 5) + (mi << 4) + ((lane >> 4) << 2);
      #pragma unroll
      for (int rg = 0; rg < 4; ++rg)
        smem[t * 257 + o + rg] = acc[mi][nt][rg];
    }
  __syncthreads();
  // bias + residual x[b][c][t]
  #pragma unroll
  for (int r = 0; r < 8; ++r) {
    int idx = (r << 9) + tid;
    int c = idx >> 4, t4 = (idx & 15) << 2;
    float4 xv = *(const float4*)&x[((size_t)(b * 256 + c)) * NPTS + t0 + t4];
    float bo = bias[c];
    smem[(t4 + 0) * 257 + c] += xv.x + bo;
    smem[(t4 + 1) * 257 + c] += xv.y + bo;
    smem[(t4 + 2) * 257 + c] += xv.z + bo;
    smem[(t4 + 3) * 257 + c] += xv.w + bo;
  }
  float g[4], be[4];
  #pragma unroll
  for (int j = 0; j < 4; ++j) {
    g[j] = gamma[lane + 64 * j];
    be[j] = beta[lane + 64 * j];
  }
  __syncthreads();
  // LayerNorm over c per t-row; 8 waves x 8 rows
  #pragma unroll
  for (int rr = 0; rr < 8; ++rr) {
    int t = (w << 3) + rr;
    float v[4];
    float sum = 0.f, sq = 0.f;
    #pragma unroll
    for (int j = 0; j < 4; ++j) {
      v[j] = smem[t * 257 + lane + 64 * j];
      sum += v[j];
      sq += v[j] * v[j];
    }
    #pragma unroll
    for (int m = 1; m < 64; m <<= 1) {
      sum += __shfl_xor(sum, m);
      sq += __shfl_xor(sq, m);
    }
    float mean = sum * (1.f / 256.f);
    float var = sq * (1.f / 256.f) - mean * mean;
    float rstd = rsqrtf(var + 1e-5f);
    #pragma unroll
    for (int j = 0; j < 4; ++j)
      smem[t * 257 + lane + 64 * j] = (v[j] - mean) * rstd * g[j] + be[j];
  }
  __syncthreads();
  // transposed store out[b][c][t]
  #pragma unroll
  for (int p = 0; p < 32; ++p) {
    int c = (p << 3) + (tid >> 6);
    int t = tid & 63;
    out[((size_t)(b * 256 + c)) * NPTS + t0 + t] = smem[t * 257 + c];
  }
}

extern "C" void kernel_launch(void* const* d_in, const int* in_sizes, int n_in,
                              void* d_out, int out_size, void* d_ws, size_t ws_size,
                              hipStream_t stream) {
  const float* x     = (const float*)d_in[0];
  const float* w_in  = (const float*)d_in[1];
  const float* b_in  = (const float*)d_in[2];
  const float* wconv = (const float*)d_in[3];
  const float* bconv = (const float*)d_in[4];
  const float* A_log = (const float*)d_in[5];
  const float* Dsk   = (const float*)d_in[6];
  const float* Bw    = (const float*)d_in[7];
  const float* Cw    = (const float*)d_in[8];
  const float* w_out = (const float*)d_in[9];
  const float* b_out = (const float*)d_in[10];
  const float* gamma = (const float*)d_in[11];
  const float* beta  = (const float*)d_in[12];
  float* ws = (float*)d_ws;
  __bf16* xbf   = (__bf16*)(ws + OFF_XBF);
  __bf16* x1b   = (__bf16*)(ws + OFF_X1B);
  __bf16* delta = (__bf16*)(ws + OFF_DELTA);
  __bf16* xsb   = (__bf16*)(ws + OFF_XSB);
  __bf16* ybf   = (__bf16*)(ws + OFF_YBF);
  float* Bm     = ws + OFF_BM;
  float* Cm     = ws + OFF_CM;
  float* carry  = ws + OFF_CARRY;
  float* carry2 = ws + OFF_CARRY2;
  float* out    = (float*)d_out;

  k_xpose<<<dim3(64, 4, 4), 256, 0, stream>>>(x, xbf);
  k_inproj<<<dim3(64, 8, 4), 256, 0, stream>>>(w_in, xbf, b_in, x1b, delta);
  k_convbc<<<dim3(256, 4), 256, 0, stream>>>(x1b, wconv, bconv, Bw, Cw, xsb, Bm, Cm);
  k_scan_local<<<dim3(NCH, 4), 512, 0, stream>>>(delta, Bm, A_log, carry);
  k_carry<<<64, 256, 0, stream>>>(carry, A_log, carry2);
  k_scan_y<<<dim3(NCH, 4), 512, 0, stream>>>(delta, xsb, Bm, Cm, A_log, Dsk, carry2, ybf);
  k_outln<<<dim3(64, 4), 512, 0, stream>>>(w_out, ybf, b_out, x, gamma, beta, out);
}

// Round 6
// 168.309 us; speedup vs baseline: 1.6959x; 1.0272x over previous
//
#include <hip/hip_runtime.h>
#include <math.h>

#define NPTS 4096
#define NB   4
#define NCH  128   // scan chunks
#define CHL  32    // chunk length (NCH*CHL == NPTS)

// ---- workspace offsets (float units) ----
#define OFF_XBF    0          // bf16 [B][N][256] x transposed
#define OFF_X1B    2097152    // bf16 [B][N][256] in_proj x1 half (bias applied)
#define OFF_DELTA  4194304    // bf16 [B][N][256] sigmoid(z+bias)
#define OFF_XSB    6291456    // bf16 [B][N][256] silu(conv)
#define OFF_YBF    8388608    // bf16 [B][N][256] scan output y
#define OFF_BM     10485760   // f32 [B][N][16]
#define OFF_CM     10747904   // f32 [B][N][16]
#define OFF_CARRY  11010048   // f32 [B][NCH][256][16] local chunk end-states
#define OFF_CARRY2 13107200   // f32 [B][NCH][256][16] exclusive-prefix carries

typedef __bf16 bf16x8 __attribute__((ext_vector_type(8)));
typedef __bf16 bf16x4 __attribute__((ext_vector_type(4)));
typedef float  f32x4  __attribute__((ext_vector_type(4)));

__device__ __forceinline__ float sigmoidf_(float v) { return 1.f / (1.f + expf(-v)); }

// ===== K0: transpose+convert x [B][C][N] fp32 -> xbf [B][N][C] bf16
__global__ __launch_bounds__(256) void k_xpose(const float* __restrict__ x,
                                               __bf16* __restrict__ xbf) {
  const int b = blockIdx.z, c0 = blockIdx.y << 6, t0 = blockIdx.x << 6;
  const int tid = threadIdx.x;
  __shared__ float tile[64 * 65];
  #pragma unroll
  for (int r = 0; r < 4; ++r) {
    int cc = (r << 4) + (tid >> 4), tt4 = (tid & 15) << 2;
    float4 v = *(const float4*)&x[((size_t)(b * 256 + c0 + cc)) * NPTS + t0 + tt4];
    tile[cc * 65 + tt4 + 0] = v.x;
    tile[cc * 65 + tt4 + 1] = v.y;
    tile[cc * 65 + tt4 + 2] = v.z;
    tile[cc * 65 + tt4 + 3] = v.w;
  }
  __syncthreads();
  #pragma unroll
  for (int r = 0; r < 4; ++r) {
    int tt = (r << 4) + (tid >> 4), cc4 = (tid & 15) << 2;
    bf16x4 o;
    o[0] = (__bf16)tile[(cc4 + 0) * 65 + tt];
    o[1] = (__bf16)tile[(cc4 + 1) * 65 + tt];
    o[2] = (__bf16)tile[(cc4 + 2) * 65 + tt];
    o[3] = (__bf16)tile[(cc4 + 3) * 65 + tt];
    *(bf16x4*)&xbf[((size_t)(b * NPTS + t0 + tt)) * 256 + c0 + cc4] = o;
  }
}

// ===== K1: in_proj MFMA GEMM with fused activation epilogue (XOR-swizzled LDS)
__global__ __launch_bounds__(256) void k_inproj(const float* __restrict__ W,
                                                const __bf16* __restrict__ Bop,
                                                const float* __restrict__ bias,
                                                __bf16* __restrict__ x1b,
                                                __bf16* __restrict__ delta) {
  const int b = blockIdx.z, o0 = blockIdx.y << 6, t0 = blockIdx.x << 6;
  const int tid = threadIdx.x, lane = tid & 63, wv = tid >> 6;
  const int mo = (wv & 1) << 5, no = (wv >> 1) << 5;
  __shared__ __align__(16) float smem[64 * 68];
  __bf16* Al = (__bf16*)smem;
  __bf16* Bl = Al + 4096;
  float* Cl = smem;

  f32x4 acc[2][2] = {};
  for (int k0 = 0; k0 < 256; k0 += 64) {
    __syncthreads();
    #pragma unroll
    for (int r = 0; r < 4; ++r) {
      int idx = (r << 8) + tid;
      int oo = idx >> 4, kk = (idx & 15) << 2;
      float4 v = *(const float4*)&W[((size_t)(o0 + oo)) * 256 + k0 + kk];
      bf16x4 p;
      p[0] = (__bf16)v.x; p[1] = (__bf16)v.y; p[2] = (__bf16)v.z; p[3] = (__bf16)v.w;
      *(bf16x4*)&Al[oo * 64 + ((((kk >> 3) ^ (oo & 7))) << 3) + (kk & 7)] = p;
    }
    #pragma unroll
    for (int r = 0; r < 2; ++r) {
      int idx = (r << 8) + tid;
      int tt = idx >> 3, ch = idx & 7;
      *(uint4*)&Bl[tt * 64 + ((ch ^ (tt & 7)) << 3)] =
          *(const uint4*)&Bop[((size_t)(b * NPTS + t0 + tt)) * 256 + k0 + (ch << 3)];
    }
    __syncthreads();
    #pragma unroll
    for (int kc = 0; kc < 64; kc += 32) {
      int ch0 = (kc >> 3) + (lane >> 4);
      int ra0 = mo + (lane & 15), ra1 = ra0 + 16;
      int rb0 = no + (lane & 15), rb1 = rb0 + 16;
      bf16x8 a0 = *(bf16x8*)&Al[ra0 * 64 + ((ch0 ^ (ra0 & 7)) << 3)];
      bf16x8 a1 = *(bf16x8*)&Al[ra1 * 64 + ((ch0 ^ (ra1 & 7)) << 3)];
      bf16x8 b0 = *(bf16x8*)&Bl[rb0 * 64 + ((ch0 ^ (rb0 & 7)) << 3)];
      bf16x8 b1 = *(bf16x8*)&Bl[rb1 * 64 + ((ch0 ^ (rb1 & 7)) << 3)];
      acc[0][0] = __builtin_amdgcn_mfma_f32_16x16x32_bf16(a0, b0, acc[0][0], 0, 0, 0);
      acc[0][1] = __builtin_amdgcn_mfma_f32_16x16x32_bf16(a0, b1, acc[0][1], 0, 0, 0);
      acc[1][0] = __builtin_amdgcn_mfma_f32_16x16x32_bf16(a1, b0, acc[1][0], 0, 0, 0);
      acc[1][1] = __builtin_amdgcn_mfma_f32_16x16x32_bf16(a1, b1, acc[1][1], 0, 0, 0);
    }
  }
  __syncthreads();
  #pragma unroll
  for (int mi = 0; mi < 2; ++mi)
    #pragma unroll
    for (int ni = 0; ni < 2; ++ni) {
      int t_loc = no + (ni << 4) + (lane & 15);
      int o_b = mo + (mi << 4) + ((lane >> 4) << 2);
      #pragma unroll
      for (int rg = 0; rg < 4; ++rg)
        Cl[t_loc * 68 + o_b + rg] = acc[mi][ni][rg];
    }
  __syncthreads();
  #pragma unroll
  for (int r = 0; r < 4; ++r) {
    int tt = (r << 4) + (tid >> 4), oo4 = (tid & 15) << 2;
    float4 v = *(float4*)&Cl[tt * 68 + oo4];
    float4 bi = *(const float4*)&bias[o0 + oo4];
    v.x += bi.x; v.y += bi.y; v.z += bi.z; v.w += bi.w;
    bf16x4 p;
    if (o0 < 256) {
      p[0] = (__bf16)v.x; p[1] = (__bf16)v.y; p[2] = (__bf16)v.z; p[3] = (__bf16)v.w;
      *(bf16x4*)&x1b[((size_t)(b * NPTS + t0 + tt)) * 256 + o0 + oo4] = p;
    } else {
      p[0] = (__bf16)sigmoidf_(v.x); p[1] = (__bf16)sigmoidf_(v.y);
      p[2] = (__bf16)sigmoidf_(v.z); p[3] = (__bf16)sigmoidf_(v.w);
      *(bf16x4*)&delta[((size_t)(b * NPTS + t0 + tt)) * 256 + (o0 - 256) + oo4] = p;
    }
  }
}

// ===== K2: fused conv+silu + B/C projection + local scan; grid (NCH, B), 512 thr
__global__ __launch_bounds__(512) void k_convscan(const __bf16* __restrict__ x1b,
                                                  const __bf16* __restrict__ delta,
                                                  const float* __restrict__ wconv,
                                                  const float* __restrict__ bconv,
                                                  const float* __restrict__ Bw,
                                                  const float* __restrict__ Cw,
                                                  const float* __restrict__ A_log,
                                                  __bf16* __restrict__ xsb,
                                                  float* __restrict__ Bm,
                                                  float* __restrict__ Cm,
                                                  float* __restrict__ carry) {
  const int b = blockIdx.y, ch = blockIdx.x, tid = threadIdx.x;
  const int t0 = ch << 5;
  __shared__ __align__(16) __bf16 xm[32][256];    // 16 KB x1 tile
  __shared__ __align__(16) __bf16 xb3[3][256];    // boundary rows t0-3..t0-1
  __shared__ __align__(16) __bf16 dtile[32][256]; // 16 KB delta tile
  __shared__ __align__(16) __bf16 Blw[16][264];   // pad 264: s-rows hit distinct banks
  __shared__ __align__(16) __bf16 Clw[16][264];
  __shared__ __align__(16) __bf16 xst[32][256];   // 16 KB silu(conv)
  __shared__ __align__(16) float bml[32][16];
  const size_t gbase = ((size_t)(b * NPTS + t0)) * 256;

  #pragma unroll
  for (int r = 0; r < 2; ++r) {
    int idx = (r << 9) + tid;            // 0..1023 uint4s
    int row = idx >> 5, col = (idx & 31) << 3;
    *(uint4*)&xm[row][col]    = *(const uint4*)&x1b[gbase + row * 256 + col];
    *(uint4*)&dtile[row][col] = *(const uint4*)&delta[gbase + row * 256 + col];
  }
  if (tid < 96) {
    int row = tid >> 5, col = (tid & 31) << 3;
    if (t0 > 0) {
      *(uint4*)&xb3[row][col] = *(const uint4*)&x1b[gbase - 3 * 256 + row * 256 + col];
    } else {
      uint4 z = make_uint4(0, 0, 0, 0);
      *(uint4*)&xb3[row][col] = z;
    }
  }
  #pragma unroll
  for (int r = 0; r < 2; ++r) {
    int idx = (r << 9) + tid;            // 0..1023 float4s
    int s = idx >> 6, col = (idx & 63) << 2;
    float4 v = *(const float4*)&Bw[s * 256 + col];
    bf16x4 p;
    p[0] = (__bf16)v.x; p[1] = (__bf16)v.y; p[2] = (__bf16)v.z; p[3] = (__bf16)v.w;
    *(bf16x4*)&Blw[s][col] = p;
    float4 u = *(const float4*)&Cw[s * 256 + col];
    bf16x4 q;
    q[0] = (__bf16)u.x; q[1] = (__bf16)u.y; q[2] = (__bf16)u.z; q[3] = (__bf16)u.w;
    *(bf16x4*)&Clw[s][col] = q;
  }
  __syncthreads();

  // conv+silu: d = tid&255, half covers 16 t
  {
    const int d = tid & 255, half = tid >> 8;
    const int tb = half << 4;
    const float4 wc = *(const float4*)&wconv[d << 2];
    const float bc = bconv[d];
    float m3, m2, m1;
    if (half == 0) {
      m3 = (float)xb3[0][d]; m2 = (float)xb3[1][d]; m1 = (float)xb3[2][d];
    } else {
      m3 = (float)xm[13][d]; m2 = (float)xm[14][d]; m1 = (float)xm[15][d];
    }
    #pragma unroll
    for (int i = 0; i < 16; ++i) {
      int t = tb + i;
      float xc = (float)xm[t][d];
      float cv = fmaf(wc.x, m3, fmaf(wc.y, m2, fmaf(wc.z, m1, fmaf(wc.w, xc, bc))));
      float sv = cv * sigmoidf_(cv);
      xst[t][d] = (__bf16)sv;
      m3 = m2; m2 = m1; m1 = xc;
    }
  }
  __syncthreads();

  // write xsb (coalesced) + B/C projection from LDS
  #pragma unroll
  for (int r = 0; r < 2; ++r) {
    int idx = (r << 9) + tid;
    int row = idx >> 5, col = (idx & 31) << 3;
    *(uint4*)&xsb[gbase + row * 256 + col] = *(uint4*)&xst[row][col];
  }
  {
    const int s = tid & 15, tl = tid >> 4;   // 32 t x 16 s
    float accB = 0.f, accC = 0.f;
    #pragma unroll 8
    for (int dd = 0; dd < 256; dd += 4) {
      bf16x4 xv = *(bf16x4*)&xst[tl][dd];
      bf16x4 bv = *(bf16x4*)&Blw[s][dd];
      bf16x4 cv = *(bf16x4*)&Clw[s][dd];
      float x0 = (float)xv[0], x1 = (float)xv[1], x2 = (float)xv[2], x3 = (float)xv[3];
      accB += x0 * (float)bv[0] + x1 * (float)bv[1] + x2 * (float)bv[2] + x3 * (float)bv[3];
      accC += x0 * (float)cv[0] + x1 * (float)cv[1] + x2 * (float)cv[2] + x3 * (float)cv[3];
    }
    bml[tl][s] = accB;
    int row = (b * NPTS + t0 + tl) * 16 + s;
    Bm[row] = accB;
    Cm[row] = accC;
  }
  __syncthreads();

  // local scan (h=0): lane-pair per d, 8 states each
  {
    const int d = tid >> 1, sh = (tid & 1) << 3;
    float a[8], h[8];
    float4 a0 = *(const float4*)&A_log[(d << 4) + sh];
    float4 a1 = *(const float4*)&A_log[(d << 4) + sh + 4];
    a[0] = -expf(a0.x); a[1] = -expf(a0.y); a[2] = -expf(a0.z); a[3] = -expf(a0.w);
    a[4] = -expf(a1.x); a[5] = -expf(a1.y); a[6] = -expf(a1.z); a[7] = -expf(a1.w);
    #pragma unroll
    for (int s = 0; s < 8; ++s) h[s] = 0.f;
    #pragma unroll
    for (int i = 0; i < CHL; ++i) {
      float u = (float)dtile[i][d];
      float4 b0 = *(float4*)&bml[i][sh];
      float4 b1 = *(float4*)&bml[i][sh + 4];
      h[0] = fmaf(a[0], h[0], u * b0.x);
      h[1] = fmaf(a[1], h[1], u * b0.y);
      h[2] = fmaf(a[2], h[2], u * b0.z);
      h[3] = fmaf(a[3], h[3], u * b0.w);
      h[4] = fmaf(a[4], h[4], u * b1.x);
      h[5] = fmaf(a[5], h[5], u * b1.y);
      h[6] = fmaf(a[6], h[6], u * b1.z);
      h[7] = fmaf(a[7], h[7], u * b1.w);
    }
    int cb = (((b * NCH + ch) << 8) + d) * 16 + sh;
    *(float4*)&carry[cb]     = make_float4(h[0], h[1], h[2], h[3]);
    *(float4*)&carry[cb + 4] = make_float4(h[4], h[5], h[6], h[7]);
  }
}

// ===== K3: exclusive-prefix carry combine, src->dst (pipelined loads)
__global__ __launch_bounds__(256) void k_carry(const float* __restrict__ src,
                                               const float* __restrict__ A_log,
                                               float* __restrict__ dst) {
  int g = blockIdx.x * 256 + threadIdx.x;
  int s = g & 15, d = (g >> 4) & 255, b = g >> 12;
  float a = -expf(A_log[(d << 4) + s]);
  float aL = a;
  #pragma unroll
  for (int i = 0; i < 5; ++i) aL *= aL;  // a^CHL (CHL=32)
  const int base = ((b * NCH) << 12) + (d << 4) + s;
  float hs = 0.f;
  float cur[16], nxt[16];
  #pragma unroll
  for (int k = 0; k < 16; ++k) cur[k] = src[base + (k << 12)];
  for (int grp = 0; grp < NCH / 16; ++grp) {
    if (grp < NCH / 16 - 1) {
      #pragma unroll
      for (int k = 0; k < 16; ++k)
        nxt[k] = src[base + (((grp + 1) * 16 + k) << 12)];
    }
    #pragma unroll
    for (int k = 0; k < 16; ++k) {
      dst[base + (((grp << 4) + k) << 12)] = hs;
      hs = fmaf(aL, hs, cur[k]);
    }
    if (grp < NCH / 16 - 1) {
      #pragma unroll
      for (int k = 0; k < 16; ++k) cur[k] = nxt[k];
    }
  }
}

// ===== K4: re-run chunks with true carry-in, y via LDS tile, coalesced write
__global__ __launch_bounds__(512) void k_scan_y(const __bf16* __restrict__ delta,
                                                const __bf16* __restrict__ xsb,
                                                const float* __restrict__ Bm,
                                                const float* __restrict__ Cm,
                                                const float* __restrict__ A_log,
                                                const float* __restrict__ Dskip,
                                                const float* __restrict__ carry2,
                                                __bf16* __restrict__ ybf) {
  const int b = blockIdx.y, ch = blockIdx.x, tid = threadIdx.x;
  const int t0 = ch << 5;
  const int d = tid >> 1, sh = (tid & 1) << 3;
  __shared__ __align__(16) __bf16 dtile[32][256];
  __shared__ __align__(16) __bf16 xst[32][256];
  __shared__ __align__(16) __bf16 yt[32][256];
  __shared__ __align__(16) float bm[32][16];
  __shared__ __align__(16) float cm[32][16];
  const size_t gbase = ((size_t)(b * NPTS + t0)) * 256;
  #pragma unroll
  for (int r = 0; r < 2; ++r) {
    int idx = (r << 9) + tid;
    int row = idx >> 5, col = (idx & 31) << 3;
    *(uint4*)&dtile[row][col] = *(const uint4*)&delta[gbase + row * 256 + col];
    *(uint4*)&xst[row][col]   = *(const uint4*)&xsb[gbase + row * 256 + col];
  }
  {
    int rowbase = (b * NPTS + t0) * 16;
    bm[0][tid] = Bm[rowbase + tid];
    cm[0][tid] = Cm[rowbase + tid];
  }
  float a[8], h[8];
  {
    float4 a0 = *(const float4*)&A_log[(d << 4) + sh];
    float4 a1 = *(const float4*)&A_log[(d << 4) + sh + 4];
    a[0] = -expf(a0.x); a[1] = -expf(a0.y); a[2] = -expf(a0.z); a[3] = -expf(a0.w);
    a[4] = -expf(a1.x); a[5] = -expf(a1.y); a[6] = -expf(a1.z); a[7] = -expf(a1.w);
  }
  {
    int cb = (((b * NCH + ch) << 8) + d) * 16 + sh;
    float4 h0 = *(const float4*)&carry2[cb];
    float4 h1 = *(const float4*)&carry2[cb + 4];
    h[0] = h0.x; h[1] = h0.y; h[2] = h0.z; h[3] = h0.w;
    h[4] = h1.x; h[5] = h1.y; h[6] = h1.z; h[7] = h1.w;
  }
  const float Dv = Dskip[d];
  __syncthreads();
  #pragma unroll
  for (int i = 0; i < CHL; ++i) {
    float u = (float)dtile[i][d];
    float4 b0 = *(float4*)&bm[i][sh];
    float4 b1 = *(float4*)&bm[i][sh + 4];
    float4 c0 = *(float4*)&cm[i][sh];
    float4 c1 = *(float4*)&cm[i][sh + 4];
    h[0] = fmaf(a[0], h[0], u * b0.x);
    h[1] = fmaf(a[1], h[1], u * b0.y);
    h[2] = fmaf(a[2], h[2], u * b0.z);
    h[3] = fmaf(a[3], h[3], u * b0.w);
    h[4] = fmaf(a[4], h[4], u * b1.x);
    h[5] = fmaf(a[5], h[5], u * b1.y);
    h[6] = fmaf(a[6], h[6], u * b1.z);
    h[7] = fmaf(a[7], h[7], u * b1.w);
    float yv = h[0] * c0.x + h[1] * c0.y + h[2] * c0.z + h[3] * c0.w
             + h[4] * c1.x + h[5] * c1.y + h[6] * c1.z + h[7] * c1.w;
    yv += __shfl_xor(yv, 1);
    if ((tid & 1) == 0) {
      float xv = (float)xst[i][d];
      yt[i][d] = (__bf16)fmaf(Dv, xv, yv);
    }
  }
  __syncthreads();
  #pragma unroll
  for (int r = 0; r < 2; ++r) {
    int idx = (r << 9) + tid;
    int row = idx >> 5, col = (idx & 31) << 3;
    *(uint4*)&ybf[gbase + row * 256 + col] = *(uint4*)&yt[row][col];
  }
}

// ===== K5: fused out_proj GEMM + bias + residual + LayerNorm + transpose
// grid (N/32, B), 512 thr = 8 waves; block: 256 o x 32 t
__global__ __launch_bounds__(512) void k_outln(const float* __restrict__ W,
                                               const __bf16* __restrict__ ybf,
                                               const float* __restrict__ bias,
                                               const float* __restrict__ x,
                                               const float* __restrict__ gamma,
                                               const float* __restrict__ beta,
                                               float* __restrict__ out) {
  const int b = blockIdx.y, t0 = blockIdx.x << 5;
  const int tid = threadIdx.x, lane = tid & 63, w = tid >> 6;
  __shared__ __align__(16) __bf16 Al[256 * 64];   // 32 KB W tile (swizzled)
  __shared__ __align__(16) __bf16 Bl[32 * 64];    // 4 KB y tile (swizzled)
  __shared__ __align__(16) float Ct[32 * 257];    // 32.9 KB epilogue

  f32x4 acc[2][2] = {};
  for (int k0 = 0; k0 < 256; k0 += 64) {
    __syncthreads();
    #pragma unroll
    for (int r = 0; r < 8; ++r) {
      int idx = (r << 9) + tid;
      int oo = idx >> 4, kk = (idx & 15) << 2;
      float4 v = *(const float4*)&W[(size_t)oo * 256 + k0 + kk];
      bf16x4 p;
      p[0] = (__bf16)v.x; p[1] = (__bf16)v.y; p[2] = (__bf16)v.z; p[3] = (__bf16)v.w;
      *(bf16x4*)&Al[oo * 64 + (((kk >> 3) ^ (oo & 7)) << 3) + (kk & 7)] = p;
    }
    if (tid < 256) {
      int tt = tid >> 3, chk = tid & 7;
      *(uint4*)&Bl[tt * 64 + ((chk ^ (tt & 7)) << 3)] =
          *(const uint4*)&ybf[((size_t)(b * NPTS + t0 + tt)) * 256 + k0 + (chk << 3)];
    }
    __syncthreads();
    #pragma unroll
    for (int kc = 0; kc < 64; kc += 32) {
      int ch0 = (kc >> 3) + (lane >> 4);
      int ra0 = (w << 5) + (lane & 15), ra1 = ra0 + 16;
      bf16x8 a0 = *(bf16x8*)&Al[ra0 * 64 + ((ch0 ^ (ra0 & 7)) << 3)];
      bf16x8 a1 = *(bf16x8*)&Al[ra1 * 64 + ((ch0 ^ (ra1 & 7)) << 3)];
      #pragma unroll
      for (int nt = 0; nt < 2; ++nt) {
        int rb = (nt << 4) + (lane & 15);
        bf16x8 bv = *(bf16x8*)&Bl[rb * 64 + ((ch0 ^ (rb & 7)) << 3)];
        acc[0][nt] = __builtin_amdgcn_mfma_f32_16x16x32_bf16(a0, bv, acc[0][nt], 0, 0, 0);
        acc[1][nt] = __builtin_amdgcn_mfma_f32_16x16x32_bf16(a1, bv, acc[1][nt], 0, 0, 0);
      }
    }
  }
  __syncthreads();
  #pragma unroll
  for (int mi = 0; mi < 2; ++mi)
    #pragma unroll
    for (int nt = 0; nt < 2; ++nt) {
      int t = (nt << 4) + (lane & 15);
      int o = (w << 5) + (mi << 4) + ((lane >> 4) << 2);
      #pragma unroll
      for (int rg = 0; rg < 4; ++rg)
        Ct[t * 257 + o + rg] = acc[mi][nt][rg];
    }
  __syncthreads();
  #pragma unroll
  for (int r = 0; r < 4; ++r) {
    int idx = (r << 9) + tid;          // 0..2047 float4s
    int c = idx >> 3, t4 = (idx & 7) << 2;
    float4 xv = *(const float4*)&x[((size_t)(b * 256 + c)) * NPTS + t0 + t4];
    float bo = bias[c];
    Ct[(t4 + 0) * 257 + c] += xv.x + bo;
    Ct[(t4 + 1) * 257 + c] += xv.y + bo;
    Ct[(t4 + 2) * 257 + c] += xv.z + bo;
    Ct[(t4 + 3) * 257 + c] += xv.w + bo;
  }
  float g[4], be[4];
  #pragma unroll
  for (int j = 0; j < 4; ++j) {
    g[j] = gamma[lane + 64 * j];
    be[j] = beta[lane + 64 * j];
  }
  __syncthreads();
  #pragma unroll
  for (int rr = 0; rr < 4; ++rr) {
    int t = (w << 2) + rr;
    float v[4];
    float sum = 0.f, sq = 0.f;
    #pragma unroll
    for (int j = 0; j < 4; ++j) {
      v[j] = Ct[t * 257 + lane + 64 * j];
      sum += v[j];
      sq += v[j] * v[j];
    }
    #pragma unroll
    for (int m = 1; m < 64; m <<= 1) {
      sum += __shfl_xor(sum, m);
      sq += __shfl_xor(sq, m);
    }
    float mean = sum * (1.f / 256.f);
    float var = sq * (1.f / 256.f) - mean * mean;
    float rstd = rsqrtf(var + 1e-5f);
    #pragma unroll
    for (int j = 0; j < 4; ++j)
      Ct[t * 257 + lane + 64 * j] = (v[j] - mean) * rstd * g[j] + be[j];
  }
  __syncthreads();
  #pragma unroll
  for (int p = 0; p < 16; ++p) {
    int c = (p << 4) + (tid >> 5);
    int t = tid & 31;
    out[((size_t)(b * 256 + c)) * NPTS + t0 + t] = Ct[t * 257 + c];
  }
}

extern "C" void kernel_launch(void* const* d_in, const int* in_sizes, int n_in,
                              void* d_out, int out_size, void* d_ws, size_t ws_size,
                              hipStream_t stream) {
  const float* x     = (const float*)d_in[0];
  const float* w_in  = (const float*)d_in[1];
  const float* b_in  = (const float*)d_in[2];
  const float* wconv = (const float*)d_in[3];
  const float* bconv = (const float*)d_in[4];
  const float* A_log = (const float*)d_in[5];
  const float* Dsk   = (const float*)d_in[6];
  const float* Bw    = (const float*)d_in[7];
  const float* Cw    = (const float*)d_in[8];
  const float* w_out = (const float*)d_in[9];
  const float* b_out = (const float*)d_in[10];
  const float* gamma = (const float*)d_in[11];
  const float* beta  = (const float*)d_in[12];
  float* ws = (float*)d_ws;
  __bf16* xbf   = (__bf16*)(ws + OFF_XBF);
  __bf16* x1b   = (__bf16*)(ws + OFF_X1B);
  __bf16* delta = (__bf16*)(ws + OFF_DELTA);
  __bf16* xsb   = (__bf16*)(ws + OFF_XSB);
  __bf16* ybf   = (__bf16*)(ws + OFF_YBF);
  float* Bm     = ws + OFF_BM;
  float* Cm     = ws + OFF_CM;
  float* carry  = ws + OFF_CARRY;
  float* carry2 = ws + OFF_CARRY2;
  float* out    = (float*)d_out;

  k_xpose<<<dim3(64, 4, 4), 256, 0, stream>>>(x, xbf);
  k_inproj<<<dim3(64, 8, 4), 256, 0, stream>>>(w_in, xbf, b_in, x1b, delta);
  k_convscan<<<dim3(NCH, 4), 512, 0, stream>>>(x1b, delta, wconv, bconv, Bw, Cw,
                                               A_log, xsb, Bm, Cm, carry);
  k_carry<<<64, 256, 0, stream>>>(carry, A_log, carry2);
  k_scan_y<<<dim3(NCH, 4), 512, 0, stream>>>(delta, xsb, Bm, Cm, A_log, Dsk, carry2, ybf);
  k_outln<<<dim3(128, 4), 512, 0, stream>>>(w_out, ybf, b_out, x, gamma, beta, out);
}

// Round 7
// 163.467 us; speedup vs baseline: 1.7461x; 1.0296x over previous
//
#include <hip/hip_runtime.h>
#include <math.h>

#define NPTS 4096
#define NB   4
#define NCH  128   // scan chunks
#define CHL  32    // chunk length (NCH*CHL == NPTS)

// ---- workspace offsets (float units); total ~13.2M floats = 52.8 MB ----
#define OFF_X1B    0          // bf16 [B][N][256] in_proj x1 half (bias applied)
#define OFF_DELTA  2097152    // bf16 [B][N][256] sigmoid(z+bias)
#define OFF_XSB    4194304    // bf16 [B][N][256] silu(conv)
#define OFF_YBF    6291456    // bf16 [B][N][256] scan output y
#define OFF_BM     8388608    // f32 [B][N][16]
#define OFF_CM     8650752    // f32 [B][N][16]
#define OFF_CARRY  8912896    // f32 [B][NCH][256][16] local chunk end-states
#define OFF_CARRY2 11010048   // f32 [B][NCH][256][16] exclusive-prefix carries
#define OFF_WBI    13107200   // bf16 [512][256] w_in
#define OFF_WBO    13172736   // bf16 [256][256] w_out
#define OFF_BWB    13205504   // bf16 [16][256] Bw
#define OFF_CWB    13207552   // bf16 [16][256] Cw

typedef __bf16 bf16x8 __attribute__((ext_vector_type(8)));
typedef __bf16 bf16x4 __attribute__((ext_vector_type(4)));
typedef float  f32x4  __attribute__((ext_vector_type(4)));

__device__ __forceinline__ float sigmoidf_(float v) { return 1.f / (1.f + expf(-v)); }

// ===== K-1: one-shot weight conversion fp32 -> bf16 (w_in, w_out, Bw, Cw)
__global__ __launch_bounds__(256) void k_prep(const float* __restrict__ w_in,
                                              const float* __restrict__ w_out,
                                              const float* __restrict__ Bw,
                                              const float* __restrict__ Cw,
                                              __bf16* __restrict__ wbi,
                                              __bf16* __restrict__ wbo,
                                              __bf16* __restrict__ bwb,
                                              __bf16* __restrict__ cwb) {
  int i = blockIdx.x * 256 + threadIdx.x;   // float4 index, 51200 total
  const float* src;
  __bf16* dst;
  int off;
  if (i < 32768)      { src = w_in;  dst = wbi; off = i; }
  else if (i < 49152) { src = w_out; dst = wbo; off = i - 32768; }
  else if (i < 50176) { src = Bw;    dst = bwb; off = i - 49152; }
  else                { src = Cw;    dst = cwb; off = i - 50176; }
  float4 v = *(const float4*)&src[off << 2];
  bf16x4 p;
  p[0] = (__bf16)v.x; p[1] = (__bf16)v.y; p[2] = (__bf16)v.z; p[3] = (__bf16)v.w;
  *(bf16x4*)&dst[off << 2] = p;
}

// ===== K1: fused transpose + in_proj MFMA GEMM + activation epilogue
// block = 64t x 512o, 512 thr (wave w -> o-range w*64); grid (N/64, B) = 1 block/CU
// x read ONCE (fp32 coalesced -> LDS bounce -> bf16 [t][c]); W bf16 A-frags direct from global (L2)
__global__ __launch_bounds__(512, 2) void k_inproj(const float* __restrict__ x,
                                                   const __bf16* __restrict__ wbf,
                                                   const float* __restrict__ bias,
                                                   __bf16* __restrict__ x1b,
                                                   __bf16* __restrict__ delta) {
  const int b = blockIdx.y, t0 = blockIdx.x << 6;
  const int tid = threadIdx.x, lane = tid & 63, w = tid >> 6;
  __shared__ __align__(16) float xb[64 * 65];     // 16.6 KB fp32 bounce
  __shared__ __align__(16) __bf16 xT[64 * 264];   // 33.8 KB [t][c], reused as epilogue stage
  // --- transpose x tile [256c][64t] fp32 -> xT bf16, 4 rounds of 64c ---
  for (int c0 = 0; c0 < 256; c0 += 64) {
    __syncthreads();
    #pragma unroll
    for (int r = 0; r < 2; ++r) {
      int idx = (r << 9) + tid;
      int cc = idx >> 4, tt4 = (idx & 15) << 2;
      float4 v = *(const float4*)&x[((size_t)(b * 256 + c0 + cc)) * NPTS + t0 + tt4];
      xb[cc * 65 + tt4 + 0] = v.x;
      xb[cc * 65 + tt4 + 1] = v.y;
      xb[cc * 65 + tt4 + 2] = v.z;
      xb[cc * 65 + tt4 + 3] = v.w;
    }
    __syncthreads();
    #pragma unroll
    for (int r = 0; r < 2; ++r) {
      int idx = (r << 9) + tid;
      int tt = idx >> 4, cc4 = (idx & 15) << 2;
      bf16x4 o;
      o[0] = (__bf16)xb[(cc4 + 0) * 65 + tt];
      o[1] = (__bf16)xb[(cc4 + 1) * 65 + tt];
      o[2] = (__bf16)xb[(cc4 + 2) * 65 + tt];
      o[3] = (__bf16)xb[(cc4 + 3) * 65 + tt];
      *(bf16x4*)&xT[tt * 264 + c0 + cc4] = o;
    }
  }
  __syncthreads();
  // --- K-loop: no barriers; A from global bf16, B from LDS ---
  const int ow = w << 6;
  const int mrow = lane & 15, klane = (lane >> 4) << 3;
  f32x4 acc[4][4] = {};
  for (int k0 = 0; k0 < 256; k0 += 32) {
    bf16x8 af[4], bx[4];
    #pragma unroll
    for (int mi = 0; mi < 4; ++mi)
      af[mi] = *(const bf16x8*)&wbf[((size_t)(ow + (mi << 4) + mrow)) * 256 + k0 + klane];
    #pragma unroll
    for (int ni = 0; ni < 4; ++ni)
      bx[ni] = *(bf16x8*)&xT[((ni << 4) + mrow) * 264 + k0 + klane];
    #pragma unroll
    for (int mi = 0; mi < 4; ++mi)
      #pragma unroll
      for (int ni = 0; ni < 4; ++ni)
        acc[mi][ni] = __builtin_amdgcn_mfma_f32_16x16x32_bf16(af[mi], bx[ni], acc[mi][ni], 0, 0, 0);
  }
  // --- epilogue: half 0 (waves 0-3, o<256) -> x1b; half 1 (waves 4-7) -> sigmoid -> delta ---
  const int orow = (lane >> 4) << 2;
  #pragma unroll
  for (int half = 0; half < 2; ++half) {
    __syncthreads();
    if ((w >> 2) == half) {
      int obase = (w & 3) << 6;
      #pragma unroll
      for (int mi = 0; mi < 4; ++mi) {
        int ol = obase + (mi << 4) + orow;
        float4 bi = *(const float4*)&bias[(half << 8) + ol];
        float bia[4] = {bi.x, bi.y, bi.z, bi.w};
        #pragma unroll
        for (int ni = 0; ni < 4; ++ni) {
          int t = (ni << 4) + mrow;
          bf16x4 p;
          #pragma unroll
          for (int rg = 0; rg < 4; ++rg) {
            float v = acc[mi][ni][rg] + bia[rg];
            p[rg] = half ? (__bf16)sigmoidf_(v) : (__bf16)v;
          }
          *(bf16x4*)&xT[t * 264 + ol] = p;
        }
      }
    }
    __syncthreads();
    __bf16* dstg = half ? delta : x1b;
    #pragma unroll
    for (int r = 0; r < 4; ++r) {
      int idx = (r << 9) + tid;
      int tt = idx >> 5, col = (idx & 31) << 3;
      *(uint4*)&dstg[((size_t)(b * NPTS + t0 + tt)) * 256 + col] = *(uint4*)&xT[tt * 264 + col];
    }
  }
}

// ===== K2: fused conv+silu + B/C projection + local scan; grid (NCH, B), 512 thr
__global__ __launch_bounds__(512) void k_convscan(const __bf16* __restrict__ x1b,
                                                  const __bf16* __restrict__ delta,
                                                  const float* __restrict__ wconv,
                                                  const float* __restrict__ bconv,
                                                  const __bf16* __restrict__ Bwb,
                                                  const __bf16* __restrict__ Cwb,
                                                  const float* __restrict__ A_log,
                                                  __bf16* __restrict__ xsb,
                                                  float* __restrict__ Bm,
                                                  float* __restrict__ Cm,
                                                  float* __restrict__ carry) {
  const int b = blockIdx.y, ch = blockIdx.x, tid = threadIdx.x;
  const int t0 = ch << 5;
  __shared__ __align__(16) __bf16 xm[32][256];
  __shared__ __align__(16) __bf16 xb3[3][256];
  __shared__ __align__(16) __bf16 dtile[32][256];
  __shared__ __align__(16) __bf16 Blw[16][264];
  __shared__ __align__(16) __bf16 Clw[16][264];
  __shared__ __align__(16) __bf16 xst[32][256];
  __shared__ __align__(16) float bml[32][16];
  const size_t gbase = ((size_t)(b * NPTS + t0)) * 256;

  #pragma unroll
  for (int r = 0; r < 2; ++r) {
    int idx = (r << 9) + tid;
    int row = idx >> 5, col = (idx & 31) << 3;
    *(uint4*)&xm[row][col]    = *(const uint4*)&x1b[gbase + row * 256 + col];
    *(uint4*)&dtile[row][col] = *(const uint4*)&delta[gbase + row * 256 + col];
  }
  if (tid < 96) {
    int row = tid >> 5, col = (tid & 31) << 3;
    if (t0 > 0) {
      *(uint4*)&xb3[row][col] = *(const uint4*)&x1b[gbase - 3 * 256 + row * 256 + col];
    } else {
      uint4 z = make_uint4(0, 0, 0, 0);
      *(uint4*)&xb3[row][col] = z;
    }
  }
  {
    int s = tid >> 5, col = (tid & 31) << 3;
    *(uint4*)&Blw[s][col] = *(const uint4*)&Bwb[s * 256 + col];
    *(uint4*)&Clw[s][col] = *(const uint4*)&Cwb[s * 256 + col];
  }
  __syncthreads();

  {
    const int d = tid & 255, half = tid >> 8;
    const int tb = half << 4;
    const float4 wc = *(const float4*)&wconv[d << 2];
    const float bc = bconv[d];
    float m3, m2, m1;
    if (half == 0) {
      m3 = (float)xb3[0][d]; m2 = (float)xb3[1][d]; m1 = (float)xb3[2][d];
    } else {
      m3 = (float)xm[13][d]; m2 = (float)xm[14][d]; m1 = (float)xm[15][d];
    }
    #pragma unroll
    for (int i = 0; i < 16; ++i) {
      int t = tb + i;
      float xc = (float)xm[t][d];
      float cv = fmaf(wc.x, m3, fmaf(wc.y, m2, fmaf(wc.z, m1, fmaf(wc.w, xc, bc))));
      float sv = cv * sigmoidf_(cv);
      xst[t][d] = (__bf16)sv;
      m3 = m2; m2 = m1; m1 = xc;
    }
  }
  __syncthreads();

  #pragma unroll
  for (int r = 0; r < 2; ++r) {
    int idx = (r << 9) + tid;
    int row = idx >> 5, col = (idx & 31) << 3;
    *(uint4*)&xsb[gbase + row * 256 + col] = *(uint4*)&xst[row][col];
  }
  {
    const int s = tid & 15, tl = tid >> 4;
    float accB = 0.f, accC = 0.f;
    #pragma unroll 8
    for (int dd = 0; dd < 256; dd += 4) {
      bf16x4 xv = *(bf16x4*)&xst[tl][dd];
      bf16x4 bv = *(bf16x4*)&Blw[s][dd];
      bf16x4 cv = *(bf16x4*)&Clw[s][dd];
      float x0 = (float)xv[0], x1 = (float)xv[1], x2 = (float)xv[2], x3 = (float)xv[3];
      accB += x0 * (float)bv[0] + x1 * (float)bv[1] + x2 * (float)bv[2] + x3 * (float)bv[3];
      accC += x0 * (float)cv[0] + x1 * (float)cv[1] + x2 * (float)cv[2] + x3 * (float)cv[3];
    }
    bml[tl][s] = accB;
    int row = (b * NPTS + t0 + tl) * 16 + s;
    Bm[row] = accB;
    Cm[row] = accC;
  }
  __syncthreads();

  {
    const int d = tid >> 1, sh = (tid & 1) << 3;
    float a[8], h[8];
    float4 a0 = *(const float4*)&A_log[(d << 4) + sh];
    float4 a1 = *(const float4*)&A_log[(d << 4) + sh + 4];
    a[0] = -expf(a0.x); a[1] = -expf(a0.y); a[2] = -expf(a0.z); a[3] = -expf(a0.w);
    a[4] = -expf(a1.x); a[5] = -expf(a1.y); a[6] = -expf(a1.z); a[7] = -expf(a1.w);
    #pragma unroll
    for (int s = 0; s < 8; ++s) h[s] = 0.f;
    #pragma unroll
    for (int i = 0; i < CHL; ++i) {
      float u = (float)dtile[i][d];
      float4 b0 = *(float4*)&bml[i][sh];
      float4 b1 = *(float4*)&bml[i][sh + 4];
      h[0] = fmaf(a[0], h[0], u * b0.x);
      h[1] = fmaf(a[1], h[1], u * b0.y);
      h[2] = fmaf(a[2], h[2], u * b0.z);
      h[3] = fmaf(a[3], h[3], u * b0.w);
      h[4] = fmaf(a[4], h[4], u * b1.x);
      h[5] = fmaf(a[5], h[5], u * b1.y);
      h[6] = fmaf(a[6], h[6], u * b1.z);
      h[7] = fmaf(a[7], h[7], u * b1.w);
    }
    int cb = (((b * NCH + ch) << 8) + d) * 16 + sh;
    *(float4*)&carry[cb]     = make_float4(h[0], h[1], h[2], h[3]);
    *(float4*)&carry[cb + 4] = make_float4(h[4], h[5], h[6], h[7]);
  }
}

// ===== K3: exclusive-prefix carry combine, src->dst (pipelined loads)
__global__ __launch_bounds__(256) void k_carry(const float* __restrict__ src,
                                               const float* __restrict__ A_log,
                                               float* __restrict__ dst) {
  int g = blockIdx.x * 256 + threadIdx.x;
  int s = g & 15, d = (g >> 4) & 255, b = g >> 12;
  float a = -expf(A_log[(d << 4) + s]);
  float aL = a;
  #pragma unroll
  for (int i = 0; i < 5; ++i) aL *= aL;  // a^CHL (CHL=32)
  const int base = ((b * NCH) << 12) + (d << 4) + s;
  float hs = 0.f;
  float cur[16], nxt[16];
  #pragma unroll
  for (int k = 0; k < 16; ++k) cur[k] = src[base + (k << 12)];
  for (int grp = 0; grp < NCH / 16; ++grp) {
    if (grp < NCH / 16 - 1) {
      #pragma unroll
      for (int k = 0; k < 16; ++k)
        nxt[k] = src[base + (((grp + 1) * 16 + k) << 12)];
    }
    #pragma unroll
    for (int k = 0; k < 16; ++k) {
      dst[base + (((grp << 4) + k) << 12)] = hs;
      hs = fmaf(aL, hs, cur[k]);
    }
    if (grp < NCH / 16 - 1) {
      #pragma unroll
      for (int k = 0; k < 16; ++k) cur[k] = nxt[k];
    }
  }
}

// ===== K4: re-run chunks with true carry-in, y via LDS tile, coalesced write
__global__ __launch_bounds__(512) void k_scan_y(const __bf16* __restrict__ delta,
                                                const __bf16* __restrict__ xsb,
                                                const float* __restrict__ Bm,
                                                const float* __restrict__ Cm,
                                                const float* __restrict__ A_log,
                                                const float* __restrict__ Dskip,
                                                const float* __restrict__ carry2,
                                                __bf16* __restrict__ ybf) {
  const int b = blockIdx.y, ch = blockIdx.x, tid = threadIdx.x;
  const int t0 = ch << 5;
  const int d = tid >> 1, sh = (tid & 1) << 3;
  __shared__ __align__(16) __bf16 dtile[32][256];
  __shared__ __align__(16) __bf16 xst[32][256];
  __shared__ __align__(16) __bf16 yt[32][256];
  __shared__ __align__(16) float bm[32][16];
  __shared__ __align__(16) float cm[32][16];
  const size_t gbase = ((size_t)(b * NPTS + t0)) * 256;
  #pragma unroll
  for (int r = 0; r < 2; ++r) {
    int idx = (r << 9) + tid;
    int row = idx >> 5, col = (idx & 31) << 3;
    *(uint4*)&dtile[row][col] = *(const uint4*)&delta[gbase + row * 256 + col];
    *(uint4*)&xst[row][col]   = *(const uint4*)&xsb[gbase + row * 256 + col];
  }
  {
    int rowbase = (b * NPTS + t0) * 16;
    bm[0][tid] = Bm[rowbase + tid];
    cm[0][tid] = Cm[rowbase + tid];
  }
  float a[8], h[8];
  {
    float4 a0 = *(const float4*)&A_log[(d << 4) + sh];
    float4 a1 = *(const float4*)&A_log[(d << 4) + sh + 4];
    a[0] = -expf(a0.x); a[1] = -expf(a0.y); a[2] = -expf(a0.z); a[3] = -expf(a0.w);
    a[4] = -expf(a1.x); a[5] = -expf(a1.y); a[6] = -expf(a1.z); a[7] = -expf(a1.w);
  }
  {
    int cb = (((b * NCH + ch) << 8) + d) * 16 + sh;
    float4 h0 = *(const float4*)&carry2[cb];
    float4 h1 = *(const float4*)&carry2[cb + 4];
    h[0] = h0.x; h[1] = h0.y; h[2] = h0.z; h[3] = h0.w;
    h[4] = h1.x; h[5] = h1.y; h[6] = h1.z; h[7] = h1.w;
  }
  const float Dv = Dskip[d];
  __syncthreads();
  #pragma unroll
  for (int i = 0; i < CHL; ++i) {
    float u = (float)dtile[i][d];
    float4 b0 = *(float4*)&bm[i][sh];
    float4 b1 = *(float4*)&bm[i][sh + 4];
    float4 c0 = *(float4*)&cm[i][sh];
    float4 c1 = *(float4*)&cm[i][sh + 4];
    h[0] = fmaf(a[0], h[0], u * b0.x);
    h[1] = fmaf(a[1], h[1], u * b0.y);
    h[2] = fmaf(a[2], h[2], u * b0.z);
    h[3] = fmaf(a[3], h[3], u * b0.w);
    h[4] = fmaf(a[4], h[4], u * b1.x);
    h[5] = fmaf(a[5], h[5], u * b1.y);
    h[6] = fmaf(a[6], h[6], u * b1.z);
    h[7] = fmaf(a[7], h[7], u * b1.w);
    float yv = h[0] * c0.x + h[1] * c0.y + h[2] * c0.z + h[3] * c0.w
             + h[4] * c1.x + h[5] * c1.y + h[6] * c1.z + h[7] * c1.w;
    yv += __shfl_xor(yv, 1);
    if ((tid & 1) == 0) {
      float xv = (float)xst[i][d];
      yt[i][d] = (__bf16)fmaf(Dv, xv, yv);
    }
  }
  __syncthreads();
  #pragma unroll
  for (int r = 0; r < 2; ++r) {
    int idx = (r << 9) + tid;
    int row = idx >> 5, col = (idx & 31) << 3;
    *(uint4*)&ybf[gbase + row * 256 + col] = *(uint4*)&yt[row][col];
  }
}

// ===== K5: fused out_proj GEMM + bias + residual + LayerNorm + transpose
// grid (N/32, B), 512 thr = 8 waves; block: 256 o x 32 t; W staged from prepped bf16
__global__ __launch_bounds__(512) void k_outln(const __bf16* __restrict__ Wb,
                                               const __bf16* __restrict__ ybf,
                                               const float* __restrict__ bias,
                                               const float* __restrict__ x,
                                               const float* __restrict__ gamma,
                                               const float* __restrict__ beta,
                                               float* __restrict__ out) {
  const int b = blockIdx.y, t0 = blockIdx.x << 5;
  const int tid = threadIdx.x, lane = tid & 63, w = tid >> 6;
  __shared__ __align__(16) __bf16 Al[256 * 64];
  __shared__ __align__(16) __bf16 Bl[32 * 64];
  __shared__ __align__(16) float Ct[32 * 257];

  f32x4 acc[2][2] = {};
  for (int k0 = 0; k0 < 256; k0 += 64) {
    __syncthreads();
    #pragma unroll
    for (int r = 0; r < 4; ++r) {
      int idx = (r << 9) + tid;          // 0..2047 uint4 = 256 rows x 8
      int oo = idx >> 3, chk = idx & 7;
      *(uint4*)&Al[oo * 64 + ((chk ^ (oo & 7)) << 3)] =
          *(const uint4*)&Wb[(size_t)oo * 256 + k0 + (chk << 3)];
    }
    if (tid < 256) {
      int tt = tid >> 3, chk = tid & 7;
      *(uint4*)&Bl[tt * 64 + ((chk ^ (tt & 7)) << 3)] =
          *(const uint4*)&ybf[((size_t)(b * NPTS + t0 + tt)) * 256 + k0 + (chk << 3)];
    }
    __syncthreads();
    #pragma unroll
    for (int kc = 0; kc < 64; kc += 32) {
      int ch0 = (kc >> 3) + (lane >> 4);
      int ra0 = (w << 5) + (lane & 15), ra1 = ra0 + 16;
      bf16x8 a0 = *(bf16x8*)&Al[ra0 * 64 + ((ch0 ^ (ra0 & 7)) << 3)];
      bf16x8 a1 = *(bf16x8*)&Al[ra1 * 64 + ((ch0 ^ (ra1 & 7)) << 3)];
      #pragma unroll
      for (int nt = 0; nt < 2; ++nt) {
        int rb = (nt << 4) + (lane & 15);
        bf16x8 bv = *(bf16x8*)&Bl[rb * 64 + ((ch0 ^ (rb & 7)) << 3)];
        acc[0][nt] = __builtin_amdgcn_mfma_f32_16x16x32_bf16(a0, bv, acc[0][nt], 0, 0, 0);
        acc[1][nt] = __builtin_amdgcn_mfma_f32_16x16x32_bf16(a1, bv, acc[1][nt], 0, 0, 0);
      }
    }
  }
  __syncthreads();
  #pragma unroll
  for (int mi = 0; mi < 2; ++mi)
    #pragma unroll
    for (int nt = 0; nt < 2; ++nt) {
      int t = (nt << 4) + (lane & 15);
      int o = (w << 5) + (mi << 4) + ((lane >> 4) << 2);
      #pragma unroll
      for (int rg = 0; rg < 4; ++rg)
        Ct[t * 257 + o + rg] = acc[mi][nt][rg];
    }
  __syncthreads();
  #pragma unroll
  for (int r = 0; r < 4; ++r) {
    int idx = (r << 9) + tid;
    int c = idx >> 3, t4 = (idx & 7) << 2;
    float4 xv = *(const float4*)&x[((size_t)(b * 256 + c)) * NPTS + t0 + t4];
    float bo = bias[c];
    Ct[(t4 + 0) * 257 + c] += xv.x + bo;
    Ct[(t4 + 1) * 257 + c] += xv.y + bo;
    Ct[(t4 + 2) * 257 + c] += xv.z + bo;
    Ct[(t4 + 3) * 257 + c] += xv.w + bo;
  }
  float g[4], be[4];
  #pragma unroll
  for (int j = 0; j < 4; ++j) {
    g[j] = gamma[lane + 64 * j];
    be[j] = beta[lane + 64 * j];
  }
  __syncthreads();
  #pragma unroll
  for (int rr = 0; rr < 4; ++rr) {
    int t = (w << 2) + rr;
    float v[4];
    float sum = 0.f, sq = 0.f;
    #pragma unroll
    for (int j = 0; j < 4; ++j) {
      v[j] = Ct[t * 257 + lane + 64 * j];
      sum += v[j];
      sq += v[j] * v[j];
    }
    #pragma unroll
    for (int m = 1; m < 64; m <<= 1) {
      sum += __shfl_xor(sum, m);
      sq += __shfl_xor(sq, m);
    }
    float mean = sum * (1.f / 256.f);
    float var = sq * (1.f / 256.f) - mean * mean;
    float rstd = rsqrtf(var + 1e-5f);
    #pragma unroll
    for (int j = 0; j < 4; ++j)
      Ct[t * 257 + lane + 64 * j] = (v[j] - mean) * rstd * g[j] + be[j];
  }
  __syncthreads();
  #pragma unroll
  for (int p = 0; p < 16; ++p) {
    int c = (p << 4) + (tid >> 5);
    int t = tid & 31;
    out[((size_t)(b * 256 + c)) * NPTS + t0 + t] = Ct[t * 257 + c];
  }
}

extern "C" void kernel_launch(void* const* d_in, const int* in_sizes, int n_in,
                              void* d_out, int out_size, void* d_ws, size_t ws_size,
                              hipStream_t stream) {
  const float* x     = (const float*)d_in[0];
  const float* w_in  = (const float*)d_in[1];
  const float* b_in  = (const float*)d_in[2];
  const float* wconv = (const float*)d_in[3];
  const float* bconv = (const float*)d_in[4];
  const float* A_log = (const float*)d_in[5];
  const float* Dsk   = (const float*)d_in[6];
  const float* Bw    = (const float*)d_in[7];
  const float* Cw    = (const float*)d_in[8];
  const float* w_out = (const float*)d_in[9];
  const float* b_out = (const float*)d_in[10];
  const float* gamma = (const float*)d_in[11];
  const float* beta  = (const float*)d_in[12];
  float* ws = (float*)d_ws;
  __bf16* x1b   = (__bf16*)(ws + OFF_X1B);
  __bf16* delta = (__bf16*)(ws + OFF_DELTA);
  __bf16* xsb   = (__bf16*)(ws + OFF_XSB);
  __bf16* ybf   = (__bf16*)(ws + OFF_YBF);
  float* Bm     = ws + OFF_BM;
  float* Cm     = ws + OFF_CM;
  float* carry  = ws + OFF_CARRY;
  float* carry2 = ws + OFF_CARRY2;
  __bf16* wbi   = (__bf16*)(ws + OFF_WBI);
  __bf16* wbo   = (__bf16*)(ws + OFF_WBO);
  __bf16* bwb   = (__bf16*)(ws + OFF_BWB);
  __bf16* cwb   = (__bf16*)(ws + OFF_CWB);
  float* out    = (float*)d_out;

  k_prep<<<200, 256, 0, stream>>>(w_in, w_out, Bw, Cw, wbi, wbo, bwb, cwb);
  k_inproj<<<dim3(64, 4), 512, 0, stream>>>(x, wbi, b_in, x1b, delta);
  k_convscan<<<dim3(NCH, 4), 512, 0, stream>>>(x1b, delta, wconv, bconv, bwb, cwb,
                                               A_log, xsb, Bm, Cm, carry);
  k_carry<<<64, 256, 0, stream>>>(carry, A_log, carry2);
  k_scan_y<<<dim3(NCH, 4), 512, 0, stream>>>(delta, xsb, Bm, Cm, A_log, Dsk, carry2, ybf);
  k_outln<<<dim3(128, 4), 512, 0, stream>>>(wbo, ybf, b_out, x, gamma, beta, out);
}